// Round 7
// baseline (1383.351 us; speedup 1.0000x reference)
//
#include <hip/hip_runtime.h>

#define H 10
#define W 11
#define HP 12
#define WP 13
#define C1 16
#define C2 32
#define PIX 110
#define K3 3520
#define NFC 256
#define NSEQ 2048
#define WINLEN 10
#define HID 64
#define NCLS 7
#define NFRAMES 20480
#define CHUNK 4096
#define FPB 4          // frames per conv block
#define LDP2 72        // LDS pitch (shorts) for 64-wide bf16 tiles (BK=64)

typedef __attribute__((ext_vector_type(8))) short bf16x8;
typedef __attribute__((ext_vector_type(4))) float f32x4;

__device__ __forceinline__ float clip01(float x){ return fminf(fmaxf(x, 0.f), 1.f); }
__device__ __forceinline__ float clip11(float x){ return fminf(fmaxf(x, -1.f), 1.f); }

__device__ __forceinline__ unsigned short f2bf(float x) {
    union { float f; unsigned u; } v; v.f = x;
    unsigned r = v.u + 0x7FFFu + ((v.u >> 16) & 1u);
    return (unsigned short)(r >> 16);
}
__device__ __forceinline__ float bf2f(unsigned short b) {
    union { unsigned u; float f; } v; v.u = ((unsigned)b) << 16;
    return v.f;
}

// ---------------------------------------------------------------------------
// Prep: w3 (256x3520 fp32) -> hi/lo bf16 ([n][k] layout = MFMA B-fragment order)
// ---------------------------------------------------------------------------
__global__ __launch_bounds__(256)
void prep_w3(const float* __restrict__ w3, unsigned short* __restrict__ hi,
             unsigned short* __restrict__ lo)
{
    int i = blockIdx.x * 256 + threadIdx.x;
    if (i < NFC * K3) {
        float x = w3[i];
        unsigned short h = f2bf(x);
        hi[i] = h;
        lo[i] = f2bf(x - bf2f(h));
    }
}

// Prep: x-part weights of wf/wn -> wxL[kk][jj] float4 layout (fp32).
// wxL[(kk*128 + jj)*4 + e] = W[jj][kk*4+e], W = [wf_x; wn_x] (128 x 256)
__global__ __launch_bounds__(256)
void prep_wxL(const float* __restrict__ wf, const float* __restrict__ wn,
              float* __restrict__ wxL)
{
    int i = blockIdx.x * 256 + threadIdx.x;   // 0 .. 128*256-1
    if (i < 128 * 256) {
        int kk = i >> 9, jj = (i >> 2) & 127, e = i & 3;
        int k = kk * 4 + e;
        float v = (jj < 64) ? wf[jj * 320 + k] : wn[(jj - 64) * 320 + k];
        wxL[i] = v;
    }
}

// Prep: h-part weights -> wfhL/wnhL [kk][j] float4 layout (fp32, 16 kk x 64 j)
__global__ __launch_bounds__(256)
void prep_whL(const float* __restrict__ wf, const float* __restrict__ wn,
              float* __restrict__ wfhL, float* __restrict__ wnhL)
{
    int i2 = blockIdx.x * 256 + threadIdx.x;  // 0 .. 8191
    if (i2 < 8192) {
        int sel = i2 >> 12, i = i2 & 4095;
        int kk = i >> 8, j = (i >> 2) & 63, e = i & 3;
        const float* src = sel ? wn : wf;
        float v = src[j * 320 + 256 + kk * 4 + e];
        (sel ? wnhL : wfhL)[i] = v;
    }
}

// ---------------------------------------------------------------------------
// Kernel 1: jitter + conv1 + clip + conv2 + clip, 4 frames per 320-thread block.
// conv2 thread = (frame, out-row, c2-group-of-4): x rows in regs, reused
// across 4 c2 -> 8x fewer LDS reads than one-c2-per-thread.
// Output a2 stored as hi/lo bf16 planes (split once here).
// ---------------------------------------------------------------------------
__global__ __launch_bounds__(320)
void conv_fused(const float* __restrict__ input, const float* __restrict__ noise,
                const float* __restrict__ gw1, const float* __restrict__ gw2,
                unsigned short* __restrict__ a2h, unsigned short* __restrict__ a2l,
                int frame0)
{
    __shared__ float xinp[FPB][HP * WP];
    __shared__ float a1p[FPB][C1][HP * WP];
    __shared__ float s_w1[C1 * 9];
    __shared__ float s_w2p[C2 * 145];   // 144 + 1 pad per c2 (bank spread)

    const int tid = threadIdx.x;
    const int fbase = frame0 + blockIdx.x * FPB;

    for (int i = tid; i < C1 * 9; i += 320) s_w1[i] = gw1[i];
    for (int i = tid; i < C2 * 144; i += 320) {
        int c2 = i / 144, r = i - c2 * 144;
        s_w2p[c2 * 145 + r] = gw2[i];
    }
    for (int i = tid; i < FPB * HP * WP; i += 320) (&xinp[0][0])[i] = 0.f;
    for (int i = tid; i < FPB * C1 * HP * WP; i += 320) (&a1p[0][0][0])[i] = 0.f;
    __syncthreads();

    // jitter: 4 x 110
    for (int i = tid; i < FPB * PIX; i += 320) {
        int fl = i / PIX, p = i - fl * PIX;
        int pi = p / W, pj = p - pi * W;
        size_t g = (size_t)(fbase + fl) * PIX + p;
        xinp[fl][(pi + 1) * WP + pj + 1] = input[g] * (1.f + noise[g] / 20.f);
    }
    __syncthreads();

    // conv1: 4 x 16 x 110
    for (int i = tid; i < FPB * C1 * PIX; i += 320) {
        int fl = i / (C1 * PIX), rem = i - fl * (C1 * PIX);
        int c = rem / PIX, p = rem - c * PIX;
        int pi = p / W, pj = p - pi * W;
        const float* wr = &s_w1[c * 9];
        const float* xp = &xinp[fl][pi * WP + pj];
        float acc = xp[0]*wr[0] + xp[1]*wr[1] + xp[2]*wr[2]
                  + xp[WP]*wr[3] + xp[WP+1]*wr[4] + xp[WP+2]*wr[5]
                  + xp[2*WP]*wr[6] + xp[2*WP+1]*wr[7] + xp[2*WP+2]*wr[8];
        a1p[fl][c][(pi + 1) * WP + pj + 1] = clip01(acc);
    }
    __syncthreads();

    // conv2: thread = (fl, out-row i, c2-group g of 4)
    {
        const int fl = tid / 80;
        const int r  = tid - fl * 80;
        const int i  = r >> 3;        // 0..9
        const int g  = r & 7;         // 0..7

        float acc[4][W];
        #pragma unroll
        for (int cc = 0; cc < 4; ++cc)
            #pragma unroll
            for (int j = 0; j < W; ++j) acc[cc][j] = 0.f;

        for (int ci = 0; ci < C1; ++ci) {
            const float* xb = &a1p[fl][ci][i * WP];
            float x0[WP], x1[WP], x2[WP];
            #pragma unroll
            for (int c = 0; c < WP; ++c) { x0[c] = xb[c]; x1[c] = xb[WP + c]; x2[c] = xb[2 * WP + c]; }
            #pragma unroll
            for (int cc = 0; cc < 4; ++cc) {
                const float* wp = &s_w2p[(g * 4 + cc) * 145 + ci * 9];
                float w0 = wp[0], w1 = wp[1], w2 = wp[2];
                float w3 = wp[3], w4 = wp[4], w5 = wp[5];
                float w6 = wp[6], w7 = wp[7], w8 = wp[8];
                #pragma unroll
                for (int j = 0; j < W; ++j) {
                    acc[cc][j] += x0[j]*w0 + x0[j+1]*w1 + x0[j+2]*w2
                                + x1[j]*w3 + x1[j+1]*w4 + x1[j+2]*w5
                                + x2[j]*w6 + x2[j+1]*w7 + x2[j+2]*w8;
                }
            }
        }
        const int fr = blockIdx.x * FPB + fl;   // chunk-local frame
        #pragma unroll
        for (int cc = 0; cc < 4; ++cc) {
            size_t base = (size_t)fr * K3 + (g * 4 + cc) * PIX + i * W;
            #pragma unroll
            for (int j = 0; j < W; ++j) {
                float v = clip01(acc[cc][j]);
                unsigned short hh = f2bf(v);
                a2h[base + j] = hh;
                a2l[base + j] = f2bf(v - bf2f(hh));
            }
        }
    }
}

// ---------------------------------------------------------------------------
// Kernel 2: fc3 via bf16x3 split MFMA, NO clip (partials). 256 thr = 4 waves,
// tile 64x64, wave-tile 32x32, BK=64, reg-staged prefetch, split-K over
// blockIdx.z (z0: k 0..1791, 28 iters; z1: k 1792..3519, 27 iters).
// ---------------------------------------------------------------------------
__global__ __launch_bounds__(256)
void gemm_fc3(const unsigned short* __restrict__ Ah, const unsigned short* __restrict__ Al,
              const unsigned short* __restrict__ Bh, const unsigned short* __restrict__ Bl,
              float* __restrict__ xsp0, float* __restrict__ xsp1)
{
    __shared__ unsigned short As_h[64 * LDP2];
    __shared__ unsigned short As_l[64 * LDP2];
    __shared__ unsigned short Bs_h[64 * LDP2];
    __shared__ unsigned short Bs_l[64 * LDP2];

    const int tid  = threadIdx.x;
    const int lane = tid & 63;
    const int wid  = tid >> 6;
    const int wm   = wid >> 1, wn = wid & 1;
    const int bm   = blockIdx.x * 64;
    const int bn   = blockIdx.y * 64;
    const int z    = blockIdx.z;
    const int kb0  = z * 1792;
    const int NT   = z ? 27 : 28;
    const int lr   = lane & 15;
    const int ko   = (lane >> 4) * 8;

    const int srow = tid >> 3;          // 0..31 .. with p gives 0..63
    const int sq   = tid & 7;           // uint4-column

    f32x4 acc[2][2];
    #pragma unroll
    for (int mi = 0; mi < 2; ++mi)
        #pragma unroll
        for (int ni = 0; ni < 2; ++ni) { f32x4 zz = {0,0,0,0}; acc[mi][ni] = zz; }

    uint4 rAh[2], rAl[2], rBh[2], rBl[2];

    // prologue: load tile 0
    #pragma unroll
    for (int p = 0; p < 2; ++p) {
        int row = srow + p * 32;
        size_t ga = (size_t)(bm + row) * K3 + kb0 + sq * 8;
        size_t gb = (size_t)(bn + row) * K3 + kb0 + sq * 8;
        rAh[p] = *(const uint4*)(Ah + ga);
        rAl[p] = *(const uint4*)(Al + ga);
        rBh[p] = *(const uint4*)(Bh + gb);
        rBl[p] = *(const uint4*)(Bl + gb);
    }

    for (int t = 0; t < NT; ++t) {
        __syncthreads();   // prior iter's LDS reads complete
        #pragma unroll
        for (int p = 0; p < 2; ++p) {
            int row = srow + p * 32;
            *(uint4*)&As_h[row * LDP2 + sq * 8] = rAh[p];
            *(uint4*)&As_l[row * LDP2 + sq * 8] = rAl[p];
            *(uint4*)&Bs_h[row * LDP2 + sq * 8] = rBh[p];
            *(uint4*)&Bs_l[row * LDP2 + sq * 8] = rBl[p];
        }
        __syncthreads();

        if (t + 1 < NT) {
            int kb = kb0 + (t + 1) * 64;
            #pragma unroll
            for (int p = 0; p < 2; ++p) {
                int row = srow + p * 32;
                size_t ga = (size_t)(bm + row) * K3 + kb + sq * 8;
                size_t gb = (size_t)(bn + row) * K3 + kb + sq * 8;
                rAh[p] = *(const uint4*)(Ah + ga);
                rAl[p] = *(const uint4*)(Al + ga);
                rBh[p] = *(const uint4*)(Bh + gb);
                rBl[p] = *(const uint4*)(Bl + gb);
            }
        }

        #pragma unroll
        for (int kk = 0; kk < 64; kk += 32) {
            bf16x8 ah[2], al2[2], bh[2], bl[2];
            #pragma unroll
            for (int mi = 0; mi < 2; ++mi) {
                int row = wm * 32 + mi * 16 + lr;
                ah[mi]  = *(const bf16x8*)&As_h[row * LDP2 + kk + ko];
                al2[mi] = *(const bf16x8*)&As_l[row * LDP2 + kk + ko];
            }
            #pragma unroll
            for (int ni = 0; ni < 2; ++ni) {
                int row = wn * 32 + ni * 16 + lr;
                bh[ni] = *(const bf16x8*)&Bs_h[row * LDP2 + kk + ko];
                bl[ni] = *(const bf16x8*)&Bs_l[row * LDP2 + kk + ko];
            }
            #pragma unroll
            for (int mi = 0; mi < 2; ++mi)
                #pragma unroll
                for (int ni = 0; ni < 2; ++ni) {
                    acc[mi][ni] = __builtin_amdgcn_mfma_f32_16x16x32_bf16(ah[mi],  bh[ni], acc[mi][ni], 0, 0, 0);
                    acc[mi][ni] = __builtin_amdgcn_mfma_f32_16x16x32_bf16(ah[mi],  bl[ni], acc[mi][ni], 0, 0, 0);
                    acc[mi][ni] = __builtin_amdgcn_mfma_f32_16x16x32_bf16(al2[mi], bh[ni], acc[mi][ni], 0, 0, 0);
                }
        }
    }

    float* xsp = z ? xsp1 : xsp0;
    #pragma unroll
    for (int mi = 0; mi < 2; ++mi) {
        int row0 = bm + wm * 32 + mi * 16 + (lane >> 4) * 4;
        #pragma unroll
        for (int ni = 0; ni < 2; ++ni) {
            int col = bn + wn * 32 + ni * 16 + lr;
            #pragma unroll
            for (int r = 0; r < 4; ++r)
                xsp[(size_t)(row0 + r) * NFC + col] = acc[mi][ni][r];
        }
    }
}

// ---------------------------------------------------------------------------
// Kernel 3: XFN = clip01(xsp0+xsp1) @ Wx^T  (per chunk; M=4096, N=128, K=256)
// fp32 VALU, 1024 threads = 8 rows x 128 cols. Fuses split-K add + clip.
// ---------------------------------------------------------------------------
__global__ __launch_bounds__(1024)
void xgate_kernel(const float* __restrict__ xsp0, const float* __restrict__ xsp1,
                  const float* __restrict__ wxL, float* __restrict__ XFN, int frame0)
{
    __shared__ float xrow[8][NFC];
    const int tid = threadIdx.x;
    const int r8 = tid >> 7;         // 0..7
    const int j  = tid & 127;        // 0..127

    #pragma unroll
    for (int p = 0; p < 2; ++p) {
        int i = tid + p * 1024;      // 0..2047
        int r = i >> 8, c = i & 255;
        size_t src = (size_t)(blockIdx.x * 8 + r) * NFC + c;
        xrow[r][c] = clip01(xsp0[src] + xsp1[src]);
    }
    __syncthreads();

    const float4* wx4 = (const float4*)wxL;
    float af = 0.f;
    #pragma unroll 8
    for (int kk = 0; kk < 64; ++kk) {
        float4 w4 = wx4[kk * 128 + j];
        float4 x4 = *(const float4*)&xrow[r8][kk * 4];
        af += w4.x * x4.x + w4.y * x4.y + w4.z * x4.z + w4.w * x4.w;
    }
    XFN[(size_t)(frame0 + blockIdx.x * 8 + r8) * 128 + j] = af;
}

// ---------------------------------------------------------------------------
// Kernel 4: MGU recurrence on h-part only (x-part precomputed in XFN) + fc5.
// 4 seqs per 256-thread block, 512 blocks. Both 64x64 h-weights in LDS.
// ---------------------------------------------------------------------------
__global__ __launch_bounds__(256)
void mgu_kernel(const float* __restrict__ XFN, const float* __restrict__ wfhL_g,
                const float* __restrict__ wnhL_g, const float* __restrict__ w5,
                float* __restrict__ out)
{
    __shared__ float4 wfh[16 * 64];   // [kk][j]
    __shared__ float4 wnh[16 * 64];
    __shared__ float hs[4][HID];
    __shared__ float fhs[4][HID];

    const int tid = threadIdx.x;
    const int s   = tid >> 6;
    const int j   = tid & 63;
    const int seq = blockIdx.x * 4 + s;

    const float4* wf4 = (const float4*)wfhL_g;
    const float4* wn4 = (const float4*)wnhL_g;
    for (int i = tid; i < 1024; i += 256) { wfh[i] = wf4[i]; wnh[i] = wn4[i]; }
    hs[s][j] = 0.f;
    float hreg = 0.f;
    __syncthreads();

    for (int t = 0; t < WINLEN; ++t) {
        size_t xr = (size_t)(seq * WINLEN + t) * 128;
        float af = XFN[xr + j];
        #pragma unroll
        for (int kk = 0; kk < 16; ++kk) {
            float4 w4 = wfh[kk * 64 + j];
            float4 h4 = *(const float4*)&hs[s][kk * 4];
            af += w4.x * h4.x + w4.y * h4.y + w4.z * h4.z + w4.w * h4.w;
        }
        float f = clip01(af * (1.f / 6.f) + 0.5f);
        fhs[s][j] = f * hreg;
        __syncthreads();

        float an = XFN[xr + 64 + j];
        #pragma unroll
        for (int kk = 0; kk < 16; ++kk) {
            float4 w4 = wnh[kk * 64 + j];
            float4 h4 = *(const float4*)&fhs[s][kk * 4];
            an += w4.x * h4.x + w4.y * h4.y + w4.z * h4.z + w4.w * h4.w;
        }
        float nv = clip11(an);
        hreg = (1.f - f) * hreg + f * nv;
        hs[s][j] = hreg;
        __syncthreads();
    }

    if (tid < 4 * NCLS) {
        int s2 = tid / NCLS, c = tid - s2 * NCLS;
        float a = 0.f;
        #pragma unroll
        for (int k = 0; k < HID; ++k) a += hs[s2][k] * w5[c * HID + k];
        out[(size_t)(blockIdx.x * 4 + s2) * NCLS + c] = clip11(a);
    }
}

// ---------------------------------------------------------------------------
extern "C" void kernel_launch(void* const* d_in, const int* in_sizes, int n_in,
                              void* d_out, int out_size, void* d_ws, size_t ws_size,
                              hipStream_t stream)
{
    const float* input = (const float*)d_in[0];
    const float* noise = (const float*)d_in[1];
    const float* w1    = (const float*)d_in[2];
    const float* w2    = (const float*)d_in[3];
    const float* w3    = (const float*)d_in[4];
    const float* wf    = (const float*)d_in[5];
    const float* wn    = (const float*)d_in[6];
    const float* w5    = (const float*)d_in[7];
    float* out = (float*)d_out;

    // ws layout (~80.3 MB)
    unsigned short* w3_hi = (unsigned short*)d_ws;                 // 901120 u16
    unsigned short* w3_lo = w3_hi + (size_t)NFC * K3;              // 901120 u16
    float* wxL  = (float*)(w3_lo + (size_t)NFC * K3);              // 32768 f
    float* wfhL = wxL + 32768;                                     // 4096 f
    float* wnhL = wfhL + 4096;                                     // 4096 f
    float* XFN  = wnhL + 4096;                                     // 20480*128 f
    float* xsp0 = XFN + (size_t)NFRAMES * 128;                     // 4096*256 f
    float* xsp1 = xsp0 + (size_t)CHUNK * NFC;                      // 4096*256 f
    unsigned short* a2h = (unsigned short*)(xsp1 + (size_t)CHUNK * NFC); // 4096*3520 u16
    unsigned short* a2l = a2h + (size_t)CHUNK * K3;                      // 4096*3520 u16

    prep_w3<<<(NFC * K3 + 255) / 256, 256, 0, stream>>>(w3, w3_hi, w3_lo);
    prep_wxL<<<(128 * 256 + 255) / 256, 256, 0, stream>>>(wf, wn, wxL);
    prep_whL<<<32, 256, 0, stream>>>(wf, wn, wfhL, wnhL);

    for (int f0 = 0; f0 < NFRAMES; f0 += CHUNK) {
        conv_fused<<<CHUNK / FPB, 320, 0, stream>>>(input, noise, w1, w2, a2h, a2l, f0);
        gemm_fc3<<<dim3(CHUNK / 64, NFC / 64, 2), 256, 0, stream>>>(a2h, a2l, w3_hi, w3_lo, xsp0, xsp1);
        xgate_kernel<<<CHUNK / 8, 1024, 0, stream>>>(xsp0, xsp1, wxL, XFN, f0);
    }

    mgu_kernel<<<NSEQ / 4, 256, 0, stream>>>(XFN, wfhL, wnhL, w5, out);
}

// Round 8
// 1382.203 us; speedup vs baseline: 1.0008x; 1.0008x over previous
//
#include <hip/hip_runtime.h>

#define H 10
#define W 11
#define HP 12
#define WP 13
#define C1 16
#define C2 32
#define PIX 110
#define K3 3520
#define NFC 256
#define NSEQ 2048
#define WINLEN 10
#define HID 64
#define NCLS 7
#define NFRAMES 20480
#define CHUNK 4096
#define FPB 4          // frames per conv block
#define LDP2 72        // LDS pitch (shorts) for 64-wide bf16 tiles (BK=64)

typedef __attribute__((ext_vector_type(8))) short bf16x8;
typedef __attribute__((ext_vector_type(4))) float f32x4;

__device__ __forceinline__ float clip01(float x){ return fminf(fmaxf(x, 0.f), 1.f); }
__device__ __forceinline__ float clip11(float x){ return fminf(fmaxf(x, -1.f), 1.f); }

__device__ __forceinline__ unsigned short f2bf(float x) {
    union { float f; unsigned u; } v; v.f = x;
    unsigned r = v.u + 0x7FFFu + ((v.u >> 16) & 1u);
    return (unsigned short)(r >> 16);
}
__device__ __forceinline__ float bf2f(unsigned short b) {
    union { unsigned u; float f; } v; v.u = ((unsigned)b) << 16;
    return v.f;
}

// ---------------------------------------------------------------------------
// Prep: w3 (256x3520 fp32) -> hi/lo bf16 ([n][k] layout = MFMA B-fragment order)
// ---------------------------------------------------------------------------
__global__ __launch_bounds__(256)
void prep_w3(const float* __restrict__ w3, unsigned short* __restrict__ hi,
             unsigned short* __restrict__ lo)
{
    int i = blockIdx.x * 256 + threadIdx.x;
    if (i < NFC * K3) {
        float x = w3[i];
        unsigned short h = f2bf(x);
        hi[i] = h;
        lo[i] = f2bf(x - bf2f(h));
    }
}

// Prep: x-part weights of wf/wn -> wxL[kk][jj] float4 layout (fp32).
// wxL[(kk*128 + jj)*4 + e] = W[jj][kk*4+e], W = [wf_x; wn_x] (128 x 256)
__global__ __launch_bounds__(256)
void prep_wxL(const float* __restrict__ wf, const float* __restrict__ wn,
              float* __restrict__ wxL)
{
    int i = blockIdx.x * 256 + threadIdx.x;   // 0 .. 128*256-1
    if (i < 128 * 256) {
        int kk = i >> 9, jj = (i >> 2) & 127, e = i & 3;
        int k = kk * 4 + e;
        float v = (jj < 64) ? wf[jj * 320 + k] : wn[(jj - 64) * 320 + k];
        wxL[i] = v;
    }
}

// Prep: h-part weights -> wfhL/wnhL [kk][j] float4 layout (fp32, 16 kk x 64 j)
__global__ __launch_bounds__(256)
void prep_whL(const float* __restrict__ wf, const float* __restrict__ wn,
              float* __restrict__ wfhL, float* __restrict__ wnhL)
{
    int i2 = blockIdx.x * 256 + threadIdx.x;  // 0 .. 8191
    if (i2 < 8192) {
        int sel = i2 >> 12, i = i2 & 4095;
        int kk = i >> 8, j = (i >> 2) & 63, e = i & 3;
        const float* src = sel ? wn : wf;
        float v = src[j * 320 + 256 + kk * 4 + e];
        (sel ? wnhL : wfhL)[i] = v;
    }
}

// ---------------------------------------------------------------------------
// Kernel 1: jitter + conv1 + clip + conv2 + clip, 4 frames per 320-thread block.
// conv2 thread = (frame, out-row, c2-group-of-4): x rows in regs, reused
// across 4 c2 -> 8x fewer LDS reads than one-c2-per-thread.
// Output a2 stored as hi/lo bf16 planes (split once here).
// ---------------------------------------------------------------------------
__global__ __launch_bounds__(320)
void conv_fused(const float* __restrict__ input, const float* __restrict__ noise,
                const float* __restrict__ gw1, const float* __restrict__ gw2,
                unsigned short* __restrict__ a2h, unsigned short* __restrict__ a2l,
                int frame0)
{
    __shared__ float xinp[FPB][HP * WP];
    __shared__ float a1p[FPB][C1][HP * WP];
    __shared__ float s_w1[C1 * 9];
    __shared__ float s_w2p[C2 * 145];   // 144 + 1 pad per c2 (bank spread)

    const int tid = threadIdx.x;
    const int fbase = frame0 + blockIdx.x * FPB;

    for (int i = tid; i < C1 * 9; i += 320) s_w1[i] = gw1[i];
    for (int i = tid; i < C2 * 144; i += 320) {
        int c2 = i / 144, r = i - c2 * 144;
        s_w2p[c2 * 145 + r] = gw2[i];
    }
    for (int i = tid; i < FPB * HP * WP; i += 320) (&xinp[0][0])[i] = 0.f;
    for (int i = tid; i < FPB * C1 * HP * WP; i += 320) (&a1p[0][0][0])[i] = 0.f;
    __syncthreads();

    // jitter: 4 x 110
    for (int i = tid; i < FPB * PIX; i += 320) {
        int fl = i / PIX, p = i - fl * PIX;
        int pi = p / W, pj = p - pi * W;
        size_t g = (size_t)(fbase + fl) * PIX + p;
        xinp[fl][(pi + 1) * WP + pj + 1] = input[g] * (1.f + noise[g] / 20.f);
    }
    __syncthreads();

    // conv1: 4 x 16 x 110
    for (int i = tid; i < FPB * C1 * PIX; i += 320) {
        int fl = i / (C1 * PIX), rem = i - fl * (C1 * PIX);
        int c = rem / PIX, p = rem - c * PIX;
        int pi = p / W, pj = p - pi * W;
        const float* wr = &s_w1[c * 9];
        const float* xp = &xinp[fl][pi * WP + pj];
        float acc = xp[0]*wr[0] + xp[1]*wr[1] + xp[2]*wr[2]
                  + xp[WP]*wr[3] + xp[WP+1]*wr[4] + xp[WP+2]*wr[5]
                  + xp[2*WP]*wr[6] + xp[2*WP+1]*wr[7] + xp[2*WP+2]*wr[8];
        a1p[fl][c][(pi + 1) * WP + pj + 1] = clip01(acc);
    }
    __syncthreads();

    // conv2: thread = (fl, out-row i, c2-group g of 4)
    {
        const int fl = tid / 80;
        const int r  = tid - fl * 80;
        const int i  = r >> 3;        // 0..9
        const int g  = r & 7;         // 0..7

        float acc[4][W];
        #pragma unroll
        for (int cc = 0; cc < 4; ++cc)
            #pragma unroll
            for (int j = 0; j < W; ++j) acc[cc][j] = 0.f;

        for (int ci = 0; ci < C1; ++ci) {
            const float* xb = &a1p[fl][ci][i * WP];
            float x0[WP], x1[WP], x2[WP];
            #pragma unroll
            for (int c = 0; c < WP; ++c) { x0[c] = xb[c]; x1[c] = xb[WP + c]; x2[c] = xb[2 * WP + c]; }
            #pragma unroll
            for (int cc = 0; cc < 4; ++cc) {
                const float* wp = &s_w2p[(g * 4 + cc) * 145 + ci * 9];
                float w0 = wp[0], w1 = wp[1], w2 = wp[2];
                float w3 = wp[3], w4 = wp[4], w5 = wp[5];
                float w6 = wp[6], w7 = wp[7], w8 = wp[8];
                #pragma unroll
                for (int j = 0; j < W; ++j) {
                    acc[cc][j] += x0[j]*w0 + x0[j+1]*w1 + x0[j+2]*w2
                                + x1[j]*w3 + x1[j+1]*w4 + x1[j+2]*w5
                                + x2[j]*w6 + x2[j+1]*w7 + x2[j+2]*w8;
                }
            }
        }
        const int fr = blockIdx.x * FPB + fl;   // chunk-local frame
        #pragma unroll
        for (int cc = 0; cc < 4; ++cc) {
            size_t base = (size_t)fr * K3 + (g * 4 + cc) * PIX + i * W;
            #pragma unroll
            for (int j = 0; j < W; ++j) {
                float v = clip01(acc[cc][j]);
                unsigned short hh = f2bf(v);
                a2h[base + j] = hh;
                a2l[base + j] = f2bf(v - bf2f(hh));
            }
        }
    }
}

// ---------------------------------------------------------------------------
// Kernel 2: fc3 via bf16x3 split MFMA, NO clip (partials). 256 thr = 4 waves,
// tile 64x64, wave-tile 32x32, BK=64, reg-staged prefetch, split-K over
// blockIdx.z (z0: k 0..1791, 28 iters; z1: k 1792..3519, 27 iters).
// __launch_bounds__(256, 2): min 2 waves/EU (= our 2 blocks/CU grid) -> VGPR
// budget 256/thread so the 8 uint4 staging regs stay resident. Round-7 PMC
// showed VGPR_Count=56 (compiler targeted 8 waves/EU, <=64 VGPR) + 220 MB/
// dispatch phantom WRITE_SIZE = staging regs spilled to scratch.
// ---------------------------------------------------------------------------
__global__ __launch_bounds__(256, 2)
void gemm_fc3(const unsigned short* __restrict__ Ah, const unsigned short* __restrict__ Al,
              const unsigned short* __restrict__ Bh, const unsigned short* __restrict__ Bl,
              float* __restrict__ xsp0, float* __restrict__ xsp1)
{
    __shared__ unsigned short As_h[64 * LDP2];
    __shared__ unsigned short As_l[64 * LDP2];
    __shared__ unsigned short Bs_h[64 * LDP2];
    __shared__ unsigned short Bs_l[64 * LDP2];

    const int tid  = threadIdx.x;
    const int lane = tid & 63;
    const int wid  = tid >> 6;
    const int wm   = wid >> 1, wn = wid & 1;
    const int bm   = blockIdx.x * 64;
    const int bn   = blockIdx.y * 64;
    const int z    = blockIdx.z;
    const int kb0  = z * 1792;
    const int NT   = z ? 27 : 28;
    const int lr   = lane & 15;
    const int ko   = (lane >> 4) * 8;

    const int srow = tid >> 3;          // 0..31 .. with p gives 0..63
    const int sq   = tid & 7;           // uint4-column

    f32x4 acc[2][2];
    #pragma unroll
    for (int mi = 0; mi < 2; ++mi)
        #pragma unroll
        for (int ni = 0; ni < 2; ++ni) { f32x4 zz = {0,0,0,0}; acc[mi][ni] = zz; }

    uint4 rAh[2], rAl[2], rBh[2], rBl[2];

    // prologue: load tile 0
    #pragma unroll
    for (int p = 0; p < 2; ++p) {
        int row = srow + p * 32;
        size_t ga = (size_t)(bm + row) * K3 + kb0 + sq * 8;
        size_t gb = (size_t)(bn + row) * K3 + kb0 + sq * 8;
        rAh[p] = *(const uint4*)(Ah + ga);
        rAl[p] = *(const uint4*)(Al + ga);
        rBh[p] = *(const uint4*)(Bh + gb);
        rBl[p] = *(const uint4*)(Bl + gb);
    }

    for (int t = 0; t < NT; ++t) {
        __syncthreads();   // prior iter's LDS reads complete
        #pragma unroll
        for (int p = 0; p < 2; ++p) {
            int row = srow + p * 32;
            *(uint4*)&As_h[row * LDP2 + sq * 8] = rAh[p];
            *(uint4*)&As_l[row * LDP2 + sq * 8] = rAl[p];
            *(uint4*)&Bs_h[row * LDP2 + sq * 8] = rBh[p];
            *(uint4*)&Bs_l[row * LDP2 + sq * 8] = rBl[p];
        }
        __syncthreads();

        if (t + 1 < NT) {
            int kb = kb0 + (t + 1) * 64;
            #pragma unroll
            for (int p = 0; p < 2; ++p) {
                int row = srow + p * 32;
                size_t ga = (size_t)(bm + row) * K3 + kb + sq * 8;
                size_t gb = (size_t)(bn + row) * K3 + kb + sq * 8;
                rAh[p] = *(const uint4*)(Ah + ga);
                rAl[p] = *(const uint4*)(Al + ga);
                rBh[p] = *(const uint4*)(Bh + gb);
                rBl[p] = *(const uint4*)(Bl + gb);
            }
        }

        #pragma unroll
        for (int kk = 0; kk < 64; kk += 32) {
            bf16x8 ah[2], al2[2], bh[2], bl[2];
            #pragma unroll
            for (int mi = 0; mi < 2; ++mi) {
                int row = wm * 32 + mi * 16 + lr;
                ah[mi]  = *(const bf16x8*)&As_h[row * LDP2 + kk + ko];
                al2[mi] = *(const bf16x8*)&As_l[row * LDP2 + kk + ko];
            }
            #pragma unroll
            for (int ni = 0; ni < 2; ++ni) {
                int row = wn * 32 + ni * 16 + lr;
                bh[ni] = *(const bf16x8*)&Bs_h[row * LDP2 + kk + ko];
                bl[ni] = *(const bf16x8*)&Bs_l[row * LDP2 + kk + ko];
            }
            #pragma unroll
            for (int mi = 0; mi < 2; ++mi)
                #pragma unroll
                for (int ni = 0; ni < 2; ++ni) {
                    acc[mi][ni] = __builtin_amdgcn_mfma_f32_16x16x32_bf16(ah[mi],  bh[ni], acc[mi][ni], 0, 0, 0);
                    acc[mi][ni] = __builtin_amdgcn_mfma_f32_16x16x32_bf16(ah[mi],  bl[ni], acc[mi][ni], 0, 0, 0);
                    acc[mi][ni] = __builtin_amdgcn_mfma_f32_16x16x32_bf16(al2[mi], bh[ni], acc[mi][ni], 0, 0, 0);
                }
        }
    }

    float* xsp = z ? xsp1 : xsp0;
    #pragma unroll
    for (int mi = 0; mi < 2; ++mi) {
        int row0 = bm + wm * 32 + mi * 16 + (lane >> 4) * 4;
        #pragma unroll
        for (int ni = 0; ni < 2; ++ni) {
            int col = bn + wn * 32 + ni * 16 + lr;
            #pragma unroll
            for (int r = 0; r < 4; ++r)
                xsp[(size_t)(row0 + r) * NFC + col] = acc[mi][ni][r];
        }
    }
}

// ---------------------------------------------------------------------------
// Kernel 3: XFN = clip01(xsp0+xsp1) @ Wx^T  (per chunk; M=4096, N=128, K=256)
// fp32 VALU, 1024 threads = 8 rows x 128 cols. Fuses split-K add + clip.
// ---------------------------------------------------------------------------
__global__ __launch_bounds__(1024)
void xgate_kernel(const float* __restrict__ xsp0, const float* __restrict__ xsp1,
                  const float* __restrict__ wxL, float* __restrict__ XFN, int frame0)
{
    __shared__ float xrow[8][NFC];
    const int tid = threadIdx.x;
    const int r8 = tid >> 7;         // 0..7
    const int j  = tid & 127;        // 0..127

    #pragma unroll
    for (int p = 0; p < 2; ++p) {
        int i = tid + p * 1024;      // 0..2047
        int r = i >> 8, c = i & 255;
        size_t src = (size_t)(blockIdx.x * 8 + r) * NFC + c;
        xrow[r][c] = clip01(xsp0[src] + xsp1[src]);
    }
    __syncthreads();

    const float4* wx4 = (const float4*)wxL;
    float af = 0.f;
    #pragma unroll 8
    for (int kk = 0; kk < 64; ++kk) {
        float4 w4 = wx4[kk * 128 + j];
        float4 x4 = *(const float4*)&xrow[r8][kk * 4];
        af += w4.x * x4.x + w4.y * x4.y + w4.z * x4.z + w4.w * x4.w;
    }
    XFN[(size_t)(frame0 + blockIdx.x * 8 + r8) * 128 + j] = af;
}

// ---------------------------------------------------------------------------
// Kernel 4: MGU recurrence on h-part only (x-part precomputed in XFN) + fc5.
// 4 seqs per 256-thread block, 512 blocks. Both 64x64 h-weights in LDS.
// ---------------------------------------------------------------------------
__global__ __launch_bounds__(256)
void mgu_kernel(const float* __restrict__ XFN, const float* __restrict__ wfhL_g,
                const float* __restrict__ wnhL_g, const float* __restrict__ w5,
                float* __restrict__ out)
{
    __shared__ float4 wfh[16 * 64];   // [kk][j]
    __shared__ float4 wnh[16 * 64];
    __shared__ float hs[4][HID];
    __shared__ float fhs[4][HID];

    const int tid = threadIdx.x;
    const int s   = tid >> 6;
    const int j   = tid & 63;
    const int seq = blockIdx.x * 4 + s;

    const float4* wf4 = (const float4*)wfhL_g;
    const float4* wn4 = (const float4*)wnhL_g;
    for (int i = tid; i < 1024; i += 256) { wfh[i] = wf4[i]; wnh[i] = wn4[i]; }
    hs[s][j] = 0.f;
    float hreg = 0.f;
    __syncthreads();

    for (int t = 0; t < WINLEN; ++t) {
        size_t xr = (size_t)(seq * WINLEN + t) * 128;
        float af = XFN[xr + j];
        #pragma unroll
        for (int kk = 0; kk < 16; ++kk) {
            float4 w4 = wfh[kk * 64 + j];
            float4 h4 = *(const float4*)&hs[s][kk * 4];
            af += w4.x * h4.x + w4.y * h4.y + w4.z * h4.z + w4.w * h4.w;
        }
        float f = clip01(af * (1.f / 6.f) + 0.5f);
        fhs[s][j] = f * hreg;
        __syncthreads();

        float an = XFN[xr + 64 + j];
        #pragma unroll
        for (int kk = 0; kk < 16; ++kk) {
            float4 w4 = wnh[kk * 64 + j];
            float4 h4 = *(const float4*)&fhs[s][kk * 4];
            an += w4.x * h4.x + w4.y * h4.y + w4.z * h4.z + w4.w * h4.w;
        }
        float nv = clip11(an);
        hreg = (1.f - f) * hreg + f * nv;
        hs[s][j] = hreg;
        __syncthreads();
    }

    if (tid < 4 * NCLS) {
        int s2 = tid / NCLS, c = tid - s2 * NCLS;
        float a = 0.f;
        #pragma unroll
        for (int k = 0; k < HID; ++k) a += hs[s2][k] * w5[c * HID + k];
        out[(size_t)(blockIdx.x * 4 + s2) * NCLS + c] = clip11(a);
    }
}

// ---------------------------------------------------------------------------
extern "C" void kernel_launch(void* const* d_in, const int* in_sizes, int n_in,
                              void* d_out, int out_size, void* d_ws, size_t ws_size,
                              hipStream_t stream)
{
    const float* input = (const float*)d_in[0];
    const float* noise = (const float*)d_in[1];
    const float* w1    = (const float*)d_in[2];
    const float* w2    = (const float*)d_in[3];
    const float* w3    = (const float*)d_in[4];
    const float* wf    = (const float*)d_in[5];
    const float* wn    = (const float*)d_in[6];
    const float* w5    = (const float*)d_in[7];
    float* out = (float*)d_out;

    // ws layout (~80.3 MB)
    unsigned short* w3_hi = (unsigned short*)d_ws;                 // 901120 u16
    unsigned short* w3_lo = w3_hi + (size_t)NFC * K3;              // 901120 u16
    float* wxL  = (float*)(w3_lo + (size_t)NFC * K3);              // 32768 f
    float* wfhL = wxL + 32768;                                     // 4096 f
    float* wnhL = wfhL + 4096;                                     // 4096 f
    float* XFN  = wnhL + 4096;                                     // 20480*128 f
    float* xsp0 = XFN + (size_t)NFRAMES * 128;                     // 4096*256 f
    float* xsp1 = xsp0 + (size_t)CHUNK * NFC;                      // 4096*256 f
    unsigned short* a2h = (unsigned short*)(xsp1 + (size_t)CHUNK * NFC); // 4096*3520 u16
    unsigned short* a2l = a2h + (size_t)CHUNK * K3;                      // 4096*3520 u16

    prep_w3<<<(NFC * K3 + 255) / 256, 256, 0, stream>>>(w3, w3_hi, w3_lo);
    prep_wxL<<<(128 * 256 + 255) / 256, 256, 0, stream>>>(wf, wn, wxL);
    prep_whL<<<32, 256, 0, stream>>>(wf, wn, wfhL, wnhL);

    for (int f0 = 0; f0 < NFRAMES; f0 += CHUNK) {
        conv_fused<<<CHUNK / FPB, 320, 0, stream>>>(input, noise, w1, w2, a2h, a2l, f0);
        gemm_fc3<<<dim3(CHUNK / 64, NFC / 64, 2), 256, 0, stream>>>(a2h, a2l, w3_hi, w3_lo, xsp0, xsp1);
        xgate_kernel<<<CHUNK / 8, 1024, 0, stream>>>(xsp0, xsp1, wxL, XFN, f0);
    }

    mgu_kernel<<<NSEQ / 4, 256, 0, stream>>>(XFN, wfhL, wnhL, w5, out);
}

// Round 9
// 911.382 us; speedup vs baseline: 1.5179x; 1.5166x over previous
//
#include <hip/hip_runtime.h>

#define H 10
#define W 11
#define HP 12
#define WP 13
#define C1 16
#define C2 32
#define PIX 110
#define K3 3520
#define NFC 256
#define NSEQ 2048
#define WINLEN 10
#define HID 64
#define NCLS 7
#define NFRAMES 20480
#define CHUNK 4096
#define FPB 4          // frames per conv block

typedef __attribute__((ext_vector_type(8))) short bf16x8;
typedef __attribute__((ext_vector_type(4))) float f32x4;

__device__ __forceinline__ float clip01(float x){ return fminf(fmaxf(x, 0.f), 1.f); }
__device__ __forceinline__ float clip11(float x){ return fminf(fmaxf(x, -1.f), 1.f); }

__device__ __forceinline__ unsigned short f2bf(float x) {
    union { float f; unsigned u; } v; v.f = x;
    unsigned r = v.u + 0x7FFFu + ((v.u >> 16) & 1u);
    return (unsigned short)(r >> 16);
}
__device__ __forceinline__ float bf2f(unsigned short b) {
    union { unsigned u; float f; } v; v.u = ((unsigned)b) << 16;
    return v.f;
}

// direct global->LDS, 16B per lane (lane i lands at ldsbase + i*16)
#define GLOAD16(gp, lp) \
    __builtin_amdgcn_global_load_lds( \
        (const __attribute__((address_space(1))) unsigned int*)(gp), \
        (__attribute__((address_space(3))) unsigned int*)(lp), 16, 0, 0)

// ---------------------------------------------------------------------------
// Prep: w3 (256x3520 fp32) -> hi/lo bf16 ([n][k] layout = MFMA B-fragment order)
// ---------------------------------------------------------------------------
__global__ __launch_bounds__(256)
void prep_w3(const float* __restrict__ w3, unsigned short* __restrict__ hi,
             unsigned short* __restrict__ lo)
{
    int i = blockIdx.x * 256 + threadIdx.x;
    if (i < NFC * K3) {
        float x = w3[i];
        unsigned short h = f2bf(x);
        hi[i] = h;
        lo[i] = f2bf(x - bf2f(h));
    }
}

// Prep: x-part weights of wf/wn -> wxL[kk][jj] float4 layout (fp32).
__global__ __launch_bounds__(256)
void prep_wxL(const float* __restrict__ wf, const float* __restrict__ wn,
              float* __restrict__ wxL)
{
    int i = blockIdx.x * 256 + threadIdx.x;   // 0 .. 128*256-1
    if (i < 128 * 256) {
        int kk = i >> 9, jj = (i >> 2) & 127, e = i & 3;
        int k = kk * 4 + e;
        float v = (jj < 64) ? wf[jj * 320 + k] : wn[(jj - 64) * 320 + k];
        wxL[i] = v;
    }
}

// Prep: h-part weights -> wfhL/wnhL [kk][j] float4 layout (fp32, 16 kk x 64 j)
__global__ __launch_bounds__(256)
void prep_whL(const float* __restrict__ wf, const float* __restrict__ wn,
              float* __restrict__ wfhL, float* __restrict__ wnhL)
{
    int i2 = blockIdx.x * 256 + threadIdx.x;  // 0 .. 8191
    if (i2 < 8192) {
        int sel = i2 >> 12, i = i2 & 4095;
        int kk = i >> 8, j = (i >> 2) & 63, e = i & 3;
        const float* src = sel ? wn : wf;
        float v = src[j * 320 + 256 + kk * 4 + e];
        (sel ? wnhL : wfhL)[i] = v;
    }
}

// ---------------------------------------------------------------------------
// Kernel 1: jitter + conv1 + clip + conv2 + clip, 4 frames per 320-thread block.
// (unchanged from round 7 for attribution; next-round target)
// ---------------------------------------------------------------------------
__global__ __launch_bounds__(320)
void conv_fused(const float* __restrict__ input, const float* __restrict__ noise,
                const float* __restrict__ gw1, const float* __restrict__ gw2,
                unsigned short* __restrict__ a2h, unsigned short* __restrict__ a2l,
                int frame0)
{
    __shared__ float xinp[FPB][HP * WP];
    __shared__ float a1p[FPB][C1][HP * WP];
    __shared__ float s_w1[C1 * 9];
    __shared__ float s_w2p[C2 * 145];   // 144 + 1 pad per c2 (bank spread)

    const int tid = threadIdx.x;
    const int fbase = frame0 + blockIdx.x * FPB;

    for (int i = tid; i < C1 * 9; i += 320) s_w1[i] = gw1[i];
    for (int i = tid; i < C2 * 144; i += 320) {
        int c2 = i / 144, r = i - c2 * 144;
        s_w2p[c2 * 145 + r] = gw2[i];
    }
    for (int i = tid; i < FPB * HP * WP; i += 320) (&xinp[0][0])[i] = 0.f;
    for (int i = tid; i < FPB * C1 * HP * WP; i += 320) (&a1p[0][0][0])[i] = 0.f;
    __syncthreads();

    // jitter: 4 x 110
    for (int i = tid; i < FPB * PIX; i += 320) {
        int fl = i / PIX, p = i - fl * PIX;
        int pi = p / W, pj = p - pi * W;
        size_t g = (size_t)(fbase + fl) * PIX + p;
        xinp[fl][(pi + 1) * WP + pj + 1] = input[g] * (1.f + noise[g] / 20.f);
    }
    __syncthreads();

    // conv1: 4 x 16 x 110
    for (int i = tid; i < FPB * C1 * PIX; i += 320) {
        int fl = i / (C1 * PIX), rem = i - fl * (C1 * PIX);
        int c = rem / PIX, p = rem - c * PIX;
        int pi = p / W, pj = p - pi * W;
        const float* wr = &s_w1[c * 9];
        const float* xp = &xinp[fl][pi * WP + pj];
        float acc = xp[0]*wr[0] + xp[1]*wr[1] + xp[2]*wr[2]
                  + xp[WP]*wr[3] + xp[WP+1]*wr[4] + xp[WP+2]*wr[5]
                  + xp[2*WP]*wr[6] + xp[2*WP+1]*wr[7] + xp[2*WP+2]*wr[8];
        a1p[fl][c][(pi + 1) * WP + pj + 1] = clip01(acc);
    }
    __syncthreads();

    // conv2: thread = (fl, out-row i, c2-group g of 4)
    {
        const int fl = tid / 80;
        const int r  = tid - fl * 80;
        const int i  = r >> 3;        // 0..9
        const int g  = r & 7;         // 0..7

        float acc[4][W];
        #pragma unroll
        for (int cc = 0; cc < 4; ++cc)
            #pragma unroll
            for (int j = 0; j < W; ++j) acc[cc][j] = 0.f;

        for (int ci = 0; ci < C1; ++ci) {
            const float* xb = &a1p[fl][ci][i * WP];
            float x0[WP], x1[WP], x2[WP];
            #pragma unroll
            for (int c = 0; c < WP; ++c) { x0[c] = xb[c]; x1[c] = xb[WP + c]; x2[c] = xb[2 * WP + c]; }
            #pragma unroll
            for (int cc = 0; cc < 4; ++cc) {
                const float* wp = &s_w2p[(g * 4 + cc) * 145 + ci * 9];
                float w0 = wp[0], w1 = wp[1], w2 = wp[2];
                float w3 = wp[3], w4 = wp[4], w5 = wp[5];
                float w6 = wp[6], w7 = wp[7], w8 = wp[8];
                #pragma unroll
                for (int j = 0; j < W; ++j) {
                    acc[cc][j] += x0[j]*w0 + x0[j+1]*w1 + x0[j+2]*w2
                                + x1[j]*w3 + x1[j+1]*w4 + x1[j+2]*w5
                                + x2[j]*w6 + x2[j+1]*w7 + x2[j+2]*w8;
                }
            }
        }
        const int fr = blockIdx.x * FPB + fl;   // chunk-local frame
        #pragma unroll
        for (int cc = 0; cc < 4; ++cc) {
            size_t base = (size_t)fr * K3 + (g * 4 + cc) * PIX + i * W;
            #pragma unroll
            for (int j = 0; j < W; ++j) {
                float v = clip01(acc[cc][j]);
                unsigned short hh = f2bf(v);
                a2h[base + j] = hh;
                a2l[base + j] = f2bf(v - bf2f(hh));
            }
        }
    }
}

// ---------------------------------------------------------------------------
// Kernel 2: fc3 via bf16x3 split MFMA, global_load_lds staging (NO reg staging
// -> nothing to spill; round 7/8 showed 220 MB/dispatch scratch WRITE_SIZE from
// per-iteration register-array spills). Single 32 KB LDS buffer, 4 planes
// [64 rows][64 shorts] LINEAR (gload_lds needs contiguous lane order).
// Bank-conflict fix per rule #21 (both-sides XOR swizzle):
//   write side: lane l fetches global col-byte 16*((l&7)^(l>>3)) of its row
//   read  side: col-shorts cs -> cs ^ ((row&7)<<3)
// Wave w stages plane w (8 x 1KB gload_lds). 2 barriers per BK=64 step.
// Split-K over blockIdx.z (z0: k<1792, 28 iters; z1: rest, 27 iters).
// ---------------------------------------------------------------------------
__global__ __launch_bounds__(256)
void gemm_fc3(const unsigned short* __restrict__ Ah, const unsigned short* __restrict__ Al,
              const unsigned short* __restrict__ Bh, const unsigned short* __restrict__ Bl,
              float* __restrict__ xsp0, float* __restrict__ xsp1)
{
    __shared__ unsigned short lds[4][64 * 64];   // Ah, Al, Bh, Bl planes

    const int tid  = threadIdx.x;
    const int lane = tid & 63;
    const int wid  = tid >> 6;            // wave 0..3
    const int wm   = wid >> 1, wn = wid & 1;
    const int bm   = blockIdx.x * 64;
    const int bn   = blockIdx.y * 64;
    const int z    = blockIdx.z;
    const int kb0  = z * 1792;
    const int NT   = z ? 27 : 28;
    const int lr   = lane & 15;
    const int ko   = (lane >> 4) * 8;     // k-offset (shorts) of this lane's 8 elems

    // staging geometry: wave wid stages plane wid
    const unsigned short* gsrc;
    {
        const unsigned short* bases[4] = {Ah, Al, Bh, Bl};
        int row0 = (wid < 2) ? bm : bn;
        gsrc = bases[wid] + (size_t)row0 * K3;
    }
    const int srow = lane >> 3;                       // 0..7 (row within 8-row group)
    const int scol = ((lane & 7) ^ srow) << 3;        // swizzled col offset (shorts)

    f32x4 acc[2][2];
    #pragma unroll
    for (int mi = 0; mi < 2; ++mi)
        #pragma unroll
        for (int ni = 0; ni < 2; ++ni) { f32x4 zz = {0,0,0,0}; acc[mi][ni] = zz; }

    for (int t = 0; t < NT; ++t) {
        const int k0 = kb0 + t * 64;
        // stage: 8 instrs, instr i covers tile rows 8i..8i+7 of this wave's plane
        #pragma unroll
        for (int i = 0; i < 8; ++i) {
            GLOAD16(gsrc + (size_t)(i * 8 + srow) * K3 + k0 + scol,
                    &lds[wid][i * 512]);
        }
        __syncthreads();   // drains vmcnt -> tile ready

        #pragma unroll
        for (int kk = 0; kk < 64; kk += 32) {
            bf16x8 ah[2], al2[2], bh[2], bl[2];
            #pragma unroll
            for (int mi = 0; mi < 2; ++mi) {
                int row = wm * 32 + mi * 16 + lr;
                int cs  = (kk + ko) ^ ((row & 7) << 3);
                ah[mi]  = *(const bf16x8*)&lds[0][row * 64 + cs];
                al2[mi] = *(const bf16x8*)&lds[1][row * 64 + cs];
            }
            #pragma unroll
            for (int ni = 0; ni < 2; ++ni) {
                int row = wn * 32 + ni * 16 + lr;
                int cs  = (kk + ko) ^ ((row & 7) << 3);
                bh[ni] = *(const bf16x8*)&lds[2][row * 64 + cs];
                bl[ni] = *(const bf16x8*)&lds[3][row * 64 + cs];
            }
            #pragma unroll
            for (int mi = 0; mi < 2; ++mi)
                #pragma unroll
                for (int ni = 0; ni < 2; ++ni) {
                    acc[mi][ni] = __builtin_amdgcn_mfma_f32_16x16x32_bf16(ah[mi],  bh[ni], acc[mi][ni], 0, 0, 0);
                    acc[mi][ni] = __builtin_amdgcn_mfma_f32_16x16x32_bf16(ah[mi],  bl[ni], acc[mi][ni], 0, 0, 0);
                    acc[mi][ni] = __builtin_amdgcn_mfma_f32_16x16x32_bf16(al2[mi], bh[ni], acc[mi][ni], 0, 0, 0);
                }
        }
        __syncthreads();   // all reads done before next stage overwrites
    }

    float* xsp = z ? xsp1 : xsp0;
    #pragma unroll
    for (int mi = 0; mi < 2; ++mi) {
        int row0 = bm + wm * 32 + mi * 16 + (lane >> 4) * 4;
        #pragma unroll
        for (int ni = 0; ni < 2; ++ni) {
            int col = bn + wn * 32 + ni * 16 + lr;
            #pragma unroll
            for (int r = 0; r < 4; ++r)
                xsp[(size_t)(row0 + r) * NFC + col] = acc[mi][ni][r];
        }
    }
}

// ---------------------------------------------------------------------------
// Kernel 3: XFN = clip01(xsp0+xsp1) @ Wx^T  (per chunk; M=4096, N=128, K=256)
// ---------------------------------------------------------------------------
__global__ __launch_bounds__(1024)
void xgate_kernel(const float* __restrict__ xsp0, const float* __restrict__ xsp1,
                  const float* __restrict__ wxL, float* __restrict__ XFN, int frame0)
{
    __shared__ float xrow[8][NFC];
    const int tid = threadIdx.x;
    const int r8 = tid >> 7;         // 0..7
    const int j  = tid & 127;        // 0..127

    #pragma unroll
    for (int p = 0; p < 2; ++p) {
        int i = tid + p * 1024;      // 0..2047
        int r = i >> 8, c = i & 255;
        size_t src = (size_t)(blockIdx.x * 8 + r) * NFC + c;
        xrow[r][c] = clip01(xsp0[src] + xsp1[src]);
    }
    __syncthreads();

    const float4* wx4 = (const float4*)wxL;
    float af = 0.f;
    #pragma unroll 8
    for (int kk = 0; kk < 64; ++kk) {
        float4 w4 = wx4[kk * 128 + j];
        float4 x4 = *(const float4*)&xrow[r8][kk * 4];
        af += w4.x * x4.x + w4.y * x4.y + w4.z * x4.z + w4.w * x4.w;
    }
    XFN[(size_t)(frame0 + blockIdx.x * 8 + r8) * 128 + j] = af;
}

// ---------------------------------------------------------------------------
// Kernel 4: MGU recurrence on h-part only (x-part precomputed in XFN) + fc5.
// ---------------------------------------------------------------------------
__global__ __launch_bounds__(256)
void mgu_kernel(const float* __restrict__ XFN, const float* __restrict__ wfhL_g,
                const float* __restrict__ wnhL_g, const float* __restrict__ w5,
                float* __restrict__ out)
{
    __shared__ float4 wfh[16 * 64];   // [kk][j]
    __shared__ float4 wnh[16 * 64];
    __shared__ float hs[4][HID];
    __shared__ float fhs[4][HID];

    const int tid = threadIdx.x;
    const int s   = tid >> 6;
    const int j   = tid & 63;
    const int seq = blockIdx.x * 4 + s;

    const float4* wf4 = (const float4*)wfhL_g;
    const float4* wn4 = (const float4*)wnhL_g;
    for (int i = tid; i < 1024; i += 256) { wfh[i] = wf4[i]; wnh[i] = wn4[i]; }
    hs[s][j] = 0.f;
    float hreg = 0.f;
    __syncthreads();

    for (int t = 0; t < WINLEN; ++t) {
        size_t xr = (size_t)(seq * WINLEN + t) * 128;
        float af = XFN[xr + j];
        #pragma unroll
        for (int kk = 0; kk < 16; ++kk) {
            float4 w4 = wfh[kk * 64 + j];
            float4 h4 = *(const float4*)&hs[s][kk * 4];
            af += w4.x * h4.x + w4.y * h4.y + w4.z * h4.z + w4.w * h4.w;
        }
        float f = clip01(af * (1.f / 6.f) + 0.5f);
        fhs[s][j] = f * hreg;
        __syncthreads();

        float an = XFN[xr + 64 + j];
        #pragma unroll
        for (int kk = 0; kk < 16; ++kk) {
            float4 w4 = wnh[kk * 64 + j];
            float4 h4 = *(const float4*)&fhs[s][kk * 4];
            an += w4.x * h4.x + w4.y * h4.y + w4.z * h4.z + w4.w * h4.w;
        }
        float nv = clip11(an);
        hreg = (1.f - f) * hreg + f * nv;
        hs[s][j] = hreg;
        __syncthreads();
    }

    if (tid < 4 * NCLS) {
        int s2 = tid / NCLS, c = tid - s2 * NCLS;
        float a = 0.f;
        #pragma unroll
        for (int k = 0; k < HID; ++k) a += hs[s2][k] * w5[c * HID + k];
        out[(size_t)(blockIdx.x * 4 + s2) * NCLS + c] = clip11(a);
    }
}

// ---------------------------------------------------------------------------
extern "C" void kernel_launch(void* const* d_in, const int* in_sizes, int n_in,
                              void* d_out, int out_size, void* d_ws, size_t ws_size,
                              hipStream_t stream)
{
    const float* input = (const float*)d_in[0];
    const float* noise = (const float*)d_in[1];
    const float* w1    = (const float*)d_in[2];
    const float* w2    = (const float*)d_in[3];
    const float* w3    = (const float*)d_in[4];
    const float* wf    = (const float*)d_in[5];
    const float* wn    = (const float*)d_in[6];
    const float* w5    = (const float*)d_in[7];
    float* out = (float*)d_out;

    // ws layout (~80.3 MB)
    unsigned short* w3_hi = (unsigned short*)d_ws;                 // 901120 u16
    unsigned short* w3_lo = w3_hi + (size_t)NFC * K3;              // 901120 u16
    float* wxL  = (float*)(w3_lo + (size_t)NFC * K3);              // 32768 f
    float* wfhL = wxL + 32768;                                     // 4096 f
    float* wnhL = wfhL + 4096;                                     // 4096 f
    float* XFN  = wnhL + 4096;                                     // 20480*128 f
    float* xsp0 = XFN + (size_t)NFRAMES * 128;                     // 4096*256 f
    float* xsp1 = xsp0 + (size_t)CHUNK * NFC;                      // 4096*256 f
    unsigned short* a2h = (unsigned short*)(xsp1 + (size_t)CHUNK * NFC); // 4096*3520 u16
    unsigned short* a2l = a2h + (size_t)CHUNK * K3;                      // 4096*3520 u16

    prep_w3<<<(NFC * K3 + 255) / 256, 256, 0, stream>>>(w3, w3_hi, w3_lo);
    prep_wxL<<<(128 * 256 + 255) / 256, 256, 0, stream>>>(wf, wn, wxL);
    prep_whL<<<32, 256, 0, stream>>>(wf, wn, wfhL, wnhL);

    for (int f0 = 0; f0 < NFRAMES; f0 += CHUNK) {
        conv_fused<<<CHUNK / FPB, 320, 0, stream>>>(input, noise, w1, w2, a2h, a2l, f0);
        gemm_fc3<<<dim3(CHUNK / 64, NFC / 64, 2), 256, 0, stream>>>(a2h, a2l, w3_hi, w3_lo, xsp0, xsp1);
        xgate_kernel<<<CHUNK / 8, 1024, 0, stream>>>(xsp0, xsp1, wxL, XFN, f0);
    }

    mgu_kernel<<<NSEQ / 4, 256, 0, stream>>>(XFN, wfhL, wnhL, w5, out);
}

// Round 10
// 658.735 us; speedup vs baseline: 2.1000x; 1.3835x over previous
//
#include <hip/hip_runtime.h>

#define H 10
#define W 11
#define C1 16
#define C2 32
#define PIX 110
#define K3 3520
#define NFC 256
#define NSEQ 2048
#define WINLEN 10
#define HID 64
#define NCLS 7
#define NFRAMES 20480
#define CHUNK 4096
#define FPB 4          // frames per conv block

typedef __attribute__((ext_vector_type(8))) short bf16x8;
typedef __attribute__((ext_vector_type(4))) float f32x4;

__device__ __forceinline__ float clip01(float x){ return fminf(fmaxf(x, 0.f), 1.f); }
__device__ __forceinline__ float clip11(float x){ return fminf(fmaxf(x, -1.f), 1.f); }

__device__ __forceinline__ unsigned short f2bf(float x) {
    union { float f; unsigned u; } v; v.f = x;
    unsigned r = v.u + 0x7FFFu + ((v.u >> 16) & 1u);
    return (unsigned short)(r >> 16);
}
__device__ __forceinline__ float bf2f(unsigned short b) {
    union { unsigned u; float f; } v; v.u = ((unsigned)b) << 16;
    return v.f;
}

// direct global->LDS, 16B per lane (lane i lands at ldsbase + i*16)
#define GLOAD16(gp, lp) \
    __builtin_amdgcn_global_load_lds( \
        (const __attribute__((address_space(1))) unsigned int*)(gp), \
        (__attribute__((address_space(3))) unsigned int*)(lp), 16, 0, 0)

// ---------------------------------------------------------------------------
// Prep: w3 (256x3520 fp32) -> hi/lo bf16 ([n][k] layout)
// ---------------------------------------------------------------------------
__global__ __launch_bounds__(256)
void prep_w3(const float* __restrict__ w3, unsigned short* __restrict__ hi,
             unsigned short* __restrict__ lo)
{
    int i = blockIdx.x * 256 + threadIdx.x;
    if (i < NFC * K3) {
        float x = w3[i];
        unsigned short h = f2bf(x);
        hi[i] = h;
        lo[i] = f2bf(x - bf2f(h));
    }
}

// Prep: x-part weights of wf/wn -> wxL[kk][jj] float4 layout (fp32).
__global__ __launch_bounds__(256)
void prep_wxL(const float* __restrict__ wf, const float* __restrict__ wn,
              float* __restrict__ wxL)
{
    int i = blockIdx.x * 256 + threadIdx.x;   // 0 .. 128*256-1
    if (i < 128 * 256) {
        int kk = i >> 9, jj = (i >> 2) & 127, e = i & 3;
        int k = kk * 4 + e;
        float v = (jj < 64) ? wf[jj * 320 + k] : wn[(jj - 64) * 320 + k];
        wxL[i] = v;
    }
}

// Prep: h-part weights -> wfhL/wnhL [kk][j] float4 layout
__global__ __launch_bounds__(256)
void prep_whL(const float* __restrict__ wf, const float* __restrict__ wn,
              float* __restrict__ wfhL, float* __restrict__ wnhL)
{
    int i2 = blockIdx.x * 256 + threadIdx.x;  // 0 .. 8191
    if (i2 < 8192) {
        int sel = i2 >> 12, i = i2 & 4095;
        int kk = i >> 8, j = (i >> 2) & 63, e = i & 3;
        const float* src = sel ? wn : wf;
        float v = src[j * 320 + 256 + kk * 4 + e];
        (sel ? wnhL : wfhL)[i] = v;
    }
}

// Prep: w2 (32x16x3x3) -> shift-pair-grouped MFMA B planes.
// Bg[g][c2][k], k = s'*16+ci, shift s = 2g+s' (s=9 -> zero pad). Pitch 40.
__global__ __launch_bounds__(256)
void prep_Bg(const float* __restrict__ w2, unsigned short* __restrict__ gBgh,
             unsigned short* __restrict__ gBgl)
{
    int i = blockIdx.x * 256 + threadIdx.x;
    if (i < 6400) {
        int g = i / 1280, rem = i - g * 1280;
        int c2 = rem / 40, k = rem - c2 * 40;
        float v = 0.f;
        if (k < 32) {
            int sp = k >> 4, ci = k & 15, s = 2 * g + sp;
            if (s <= 8) v = w2[c2 * 144 + ci * 9 + s];
        }
        unsigned short hh = f2bf(v);
        gBgh[i] = hh;
        gBgl[i] = f2bf(v - bf2f(hh));
    }
}

// ---------------------------------------------------------------------------
// Kernel 1: jitter + conv1 (scalar) + conv2 (MFMA as 5 shift-pair GEMM groups).
// 256 thr = 4 waves, 4 frames/block.
// a1T layout: [pixel q (12x13 padded, pitch 16 ci)] bf16 hi/lo, col swizzle
// c ^= ((q&4)<<1) -> conflict-free b128 A-frag reads. conv2: M=128 pixel rows
// (x<11 valid), N=32 c2, K=5 groups x 32 (2 shifts x 16 ci), 3 split MFMAs.
// ---------------------------------------------------------------------------
__global__ __launch_bounds__(256)
void conv_fused(const float* __restrict__ input, const float* __restrict__ noise,
                const float* __restrict__ gw1,
                const unsigned short* __restrict__ gBgh,
                const unsigned short* __restrict__ gBgl,
                unsigned short* __restrict__ a2h, unsigned short* __restrict__ a2l,
                int frame0)
{
    __shared__ float s_w1[C1 * 9];
    __shared__ float xinp[FPB][160];                      // 12x13 padded + slack
    __shared__ __align__(16) unsigned short a1T_h[FPB][2560];  // 160 q x 16 ci
    __shared__ __align__(16) unsigned short a1T_l[FPB][2560];
    __shared__ __align__(16) unsigned short Bg_h[6400];   // 5 x 32 x pitch40
    __shared__ __align__(16) unsigned short Bg_l[6400];

    const int tid = threadIdx.x;
    const int fbase = frame0 + blockIdx.x * FPB;

    for (int i = tid; i < C1 * 9; i += 256) s_w1[i] = gw1[i];
    for (int i = tid; i < 800; i += 256) {
        ((uint4*)Bg_h)[i] = ((const uint4*)gBgh)[i];
        ((uint4*)Bg_l)[i] = ((const uint4*)gBgl)[i];
    }
    for (int i = tid; i < FPB * 160; i += 256) (&xinp[0][0])[i] = 0.f;
    {
        uint4 z = {0, 0, 0, 0};
        uint4* ph = (uint4*)&a1T_h[0][0];
        uint4* pl = (uint4*)&a1T_l[0][0];
        for (int i = tid; i < FPB * 2560 / 8; i += 256) { ph[i] = z; pl[i] = z; }
    }
    __syncthreads();

    // jitter into padded 12x13
    for (int i = tid; i < FPB * PIX; i += 256) {
        int fl = i / PIX, p = i - fl * PIX;
        int y = p / W, x = p - y * W;
        size_t g = (size_t)(fbase + fl) * PIX + p;
        xinp[fl][(y + 1) * 13 + x + 1] = input[g] * (1.f + noise[g] / 20.f);
    }
    __syncthreads();

    // conv1: items (fl, p, c) c-minor -> coalesced swizzled a1T writes
    for (int i = tid; i < FPB * 1760; i += 256) {
        int fl = i / 1760, rem = i - fl * 1760;
        int p = rem >> 4, c = rem & 15;
        int y = p / W, x = p - y * W;
        const float* wr = &s_w1[c * 9];
        const float* xp = &xinp[fl][y * 13 + x];
        float acc = xp[0]*wr[0] + xp[1]*wr[1] + xp[2]*wr[2]
                  + xp[13]*wr[3] + xp[14]*wr[4] + xp[15]*wr[5]
                  + xp[26]*wr[6] + xp[27]*wr[7] + xp[28]*wr[8];
        float v = clip01(acc);
        unsigned short hh = f2bf(v);
        int q = (y + 1) * 13 + (x + 1);
        int col = c ^ ((q & 4) << 1);      // ((q>>2)&1)<<3
        a1T_h[fl][q * 16 + col] = hh;
        a1T_l[fl][q * 16 + col] = f2bf(v - bf2f(hh));
    }
    __syncthreads();

    // conv2 via MFMA
    const int lane = tid & 63;
    const int wid  = tid >> 6;           // 4 waves; wave w: m-tiles {2w,2w+1}
    const int lr   = lane & 15;
    const int ci0  = (lane & 16) ? 8 : 0;
    const int khalf = (lane >> 4) * 8;   // B k-offset 0/8/16/24

    for (int fl = 0; fl < FPB; ++fl) {
        f32x4 acc[2][2];
        #pragma unroll
        for (int mi = 0; mi < 2; ++mi)
            #pragma unroll
            for (int ni = 0; ni < 2; ++ni) { f32x4 z = {0,0,0,0}; acc[mi][ni] = z; }

        #pragma unroll
        for (int g = 0; g < 5; ++g) {
            const int s0 = 2 * g, s1 = 2 * g + 1;
            const int offA = (s0 / 3) * 13 + s0 % 3;
            const int offB = (s1 <= 8) ? (s1 / 3) * 13 + s1 % 3 : 0;
            const int offl = (lane & 32) ? offB : offA;

            bf16x8 ah[2], al2[2], bh[2], bl[2];
            #pragma unroll
            for (int mi = 0; mi < 2; ++mi) {
                int q = (wid * 2 + mi) * 16 + lr + offl;
                int cs = q * 16 + (ci0 ^ ((q & 4) << 1));
                ah[mi]  = *(const bf16x8*)&a1T_h[fl][cs];
                al2[mi] = *(const bf16x8*)&a1T_l[fl][cs];
            }
            #pragma unroll
            for (int ni = 0; ni < 2; ++ni) {
                int bs = g * 1280 + (ni * 16 + lr) * 40 + khalf;
                bh[ni] = *(const bf16x8*)&Bg_h[bs];
                bl[ni] = *(const bf16x8*)&Bg_l[bs];
            }
            #pragma unroll
            for (int mi = 0; mi < 2; ++mi)
                #pragma unroll
                for (int ni = 0; ni < 2; ++ni) {
                    acc[mi][ni] = __builtin_amdgcn_mfma_f32_16x16x32_bf16(ah[mi],  bh[ni], acc[mi][ni], 0, 0, 0);
                    acc[mi][ni] = __builtin_amdgcn_mfma_f32_16x16x32_bf16(ah[mi],  bl[ni], acc[mi][ni], 0, 0, 0);
                    acc[mi][ni] = __builtin_amdgcn_mfma_f32_16x16x32_bf16(al2[mi], bh[ni], acc[mi][ni], 0, 0, 0);
                }
        }

        // epilogue: C row = pixel m (mask x<11), col = c2; split to hi/lo bf16
        const int fr = blockIdx.x * FPB + fl;
        #pragma unroll
        for (int mi = 0; mi < 2; ++mi) {
            int m0 = (wid * 2 + mi) * 16 + (lane >> 4) * 4;
            #pragma unroll
            for (int ni = 0; ni < 2; ++ni) {
                #pragma unroll
                for (int r = 0; r < 4; ++r) {
                    int m = m0 + r;
                    int y = m / 13, x = m - y * 13;
                    if (x < W) {
                        float v = clip01(acc[mi][ni][r]);
                        unsigned short hh = f2bf(v);
                        size_t addr = (size_t)fr * K3 + (ni * 16 + lr) * PIX + y * W + x;
                        a2h[addr] = hh;
                        a2l[addr] = f2bf(v - bf2f(hh));
                    }
                }
            }
        }
    }
}

// ---------------------------------------------------------------------------
// Kernel 2: fc3 via bf16x3 split MFMA, global_load_lds staging (round-9,
// verified: no reg staging -> no spill; both-sides XOR swizzle).
// ---------------------------------------------------------------------------
__global__ __launch_bounds__(256)
void gemm_fc3(const unsigned short* __restrict__ Ah, const unsigned short* __restrict__ Al,
              const unsigned short* __restrict__ Bh, const unsigned short* __restrict__ Bl,
              float* __restrict__ xsp0, float* __restrict__ xsp1)
{
    __shared__ unsigned short lds[4][64 * 64];   // Ah, Al, Bh, Bl planes

    const int tid  = threadIdx.x;
    const int lane = tid & 63;
    const int wid  = tid >> 6;            // wave 0..3
    const int wm   = wid >> 1, wn = wid & 1;
    const int bm   = blockIdx.x * 64;
    const int bn   = blockIdx.y * 64;
    const int z    = blockIdx.z;
    const int kb0  = z * 1792;
    const int NT   = z ? 27 : 28;
    const int lr   = lane & 15;
    const int ko   = (lane >> 4) * 8;

    const unsigned short* gsrc;
    {
        const unsigned short* bases[4] = {Ah, Al, Bh, Bl};
        int row0 = (wid < 2) ? bm : bn;
        gsrc = bases[wid] + (size_t)row0 * K3;
    }
    const int srow = lane >> 3;
    const int scol = ((lane & 7) ^ srow) << 3;

    f32x4 acc[2][2];
    #pragma unroll
    for (int mi = 0; mi < 2; ++mi)
        #pragma unroll
        for (int ni = 0; ni < 2; ++ni) { f32x4 zz = {0,0,0,0}; acc[mi][ni] = zz; }

    for (int t = 0; t < NT; ++t) {
        const int k0 = kb0 + t * 64;
        #pragma unroll
        for (int i = 0; i < 8; ++i) {
            GLOAD16(gsrc + (size_t)(i * 8 + srow) * K3 + k0 + scol,
                    &lds[wid][i * 512]);
        }
        __syncthreads();

        #pragma unroll
        for (int kk = 0; kk < 64; kk += 32) {
            bf16x8 ah[2], al2[2], bh[2], bl[2];
            #pragma unroll
            for (int mi = 0; mi < 2; ++mi) {
                int row = wm * 32 + mi * 16 + lr;
                int cs  = (kk + ko) ^ ((row & 7) << 3);
                ah[mi]  = *(const bf16x8*)&lds[0][row * 64 + cs];
                al2[mi] = *(const bf16x8*)&lds[1][row * 64 + cs];
            }
            #pragma unroll
            for (int ni = 0; ni < 2; ++ni) {
                int row = wn * 32 + ni * 16 + lr;
                int cs  = (kk + ko) ^ ((row & 7) << 3);
                bh[ni] = *(const bf16x8*)&lds[2][row * 64 + cs];
                bl[ni] = *(const bf16x8*)&lds[3][row * 64 + cs];
            }
            #pragma unroll
            for (int mi = 0; mi < 2; ++mi)
                #pragma unroll
                for (int ni = 0; ni < 2; ++ni) {
                    acc[mi][ni] = __builtin_amdgcn_mfma_f32_16x16x32_bf16(ah[mi],  bh[ni], acc[mi][ni], 0, 0, 0);
                    acc[mi][ni] = __builtin_amdgcn_mfma_f32_16x16x32_bf16(ah[mi],  bl[ni], acc[mi][ni], 0, 0, 0);
                    acc[mi][ni] = __builtin_amdgcn_mfma_f32_16x16x32_bf16(al2[mi], bh[ni], acc[mi][ni], 0, 0, 0);
                }
        }
        __syncthreads();
    }

    float* xsp = z ? xsp1 : xsp0;
    #pragma unroll
    for (int mi = 0; mi < 2; ++mi) {
        int row0 = bm + wm * 32 + mi * 16 + (lane >> 4) * 4;
        #pragma unroll
        for (int ni = 0; ni < 2; ++ni) {
            int col = bn + wn * 32 + ni * 16 + lr;
            #pragma unroll
            for (int r = 0; r < 4; ++r)
                xsp[(size_t)(row0 + r) * NFC + col] = acc[mi][ni][r];
        }
    }
}

// ---------------------------------------------------------------------------
// Kernel 3: XFN = clip01(xsp0+xsp1) @ Wx^T  (per chunk)
// ---------------------------------------------------------------------------
__global__ __launch_bounds__(1024)
void xgate_kernel(const float* __restrict__ xsp0, const float* __restrict__ xsp1,
                  const float* __restrict__ wxL, float* __restrict__ XFN, int frame0)
{
    __shared__ float xrow[8][NFC];
    const int tid = threadIdx.x;
    const int r8 = tid >> 7;
    const int j  = tid & 127;

    #pragma unroll
    for (int p = 0; p < 2; ++p) {
        int i = tid + p * 1024;
        int r = i >> 8, c = i & 255;
        size_t src = (size_t)(blockIdx.x * 8 + r) * NFC + c;
        xrow[r][c] = clip01(xsp0[src] + xsp1[src]);
    }
    __syncthreads();

    const float4* wx4 = (const float4*)wxL;
    float af = 0.f;
    #pragma unroll 8
    for (int kk = 0; kk < 64; ++kk) {
        float4 w4 = wx4[kk * 128 + j];
        float4 x4 = *(const float4*)&xrow[r8][kk * 4];
        af += w4.x * x4.x + w4.y * x4.y + w4.z * x4.z + w4.w * x4.w;
    }
    XFN[(size_t)(frame0 + blockIdx.x * 8 + r8) * 128 + j] = af;
}

// ---------------------------------------------------------------------------
// Kernel 4: MGU recurrence (h-part only) + fc5
// ---------------------------------------------------------------------------
__global__ __launch_bounds__(256)
void mgu_kernel(const float* __restrict__ XFN, const float* __restrict__ wfhL_g,
                const float* __restrict__ wnhL_g, const float* __restrict__ w5,
                float* __restrict__ out)
{
    __shared__ float4 wfh[16 * 64];
    __shared__ float4 wnh[16 * 64];
    __shared__ float hs[4][HID];
    __shared__ float fhs[4][HID];

    const int tid = threadIdx.x;
    const int s   = tid >> 6;
    const int j   = tid & 63;
    const int seq = blockIdx.x * 4 + s;

    const float4* wf4 = (const float4*)wfhL_g;
    const float4* wn4 = (const float4*)wnhL_g;
    for (int i = tid; i < 1024; i += 256) { wfh[i] = wf4[i]; wnh[i] = wn4[i]; }
    hs[s][j] = 0.f;
    float hreg = 0.f;
    __syncthreads();

    for (int t = 0; t < WINLEN; ++t) {
        size_t xr = (size_t)(seq * WINLEN + t) * 128;
        float af = XFN[xr + j];
        #pragma unroll
        for (int kk = 0; kk < 16; ++kk) {
            float4 w4 = wfh[kk * 64 + j];
            float4 h4 = *(const float4*)&hs[s][kk * 4];
            af += w4.x * h4.x + w4.y * h4.y + w4.z * h4.z + w4.w * h4.w;
        }
        float f = clip01(af * (1.f / 6.f) + 0.5f);
        fhs[s][j] = f * hreg;
        __syncthreads();

        float an = XFN[xr + 64 + j];
        #pragma unroll
        for (int kk = 0; kk < 16; ++kk) {
            float4 w4 = wnh[kk * 64 + j];
            float4 h4 = *(const float4*)&fhs[s][kk * 4];
            an += w4.x * h4.x + w4.y * h4.y + w4.z * h4.z + w4.w * h4.w;
        }
        float nv = clip11(an);
        hreg = (1.f - f) * hreg + f * nv;
        hs[s][j] = hreg;
        __syncthreads();
    }

    if (tid < 4 * NCLS) {
        int s2 = tid / NCLS, c = tid - s2 * NCLS;
        float a = 0.f;
        #pragma unroll
        for (int k = 0; k < HID; ++k) a += hs[s2][k] * w5[c * HID + k];
        out[(size_t)(blockIdx.x * 4 + s2) * NCLS + c] = clip11(a);
    }
}

// ---------------------------------------------------------------------------
extern "C" void kernel_launch(void* const* d_in, const int* in_sizes, int n_in,
                              void* d_out, int out_size, void* d_ws, size_t ws_size,
                              hipStream_t stream)
{
    const float* input = (const float*)d_in[0];
    const float* noise = (const float*)d_in[1];
    const float* w1    = (const float*)d_in[2];
    const float* w2    = (const float*)d_in[3];
    const float* w3    = (const float*)d_in[4];
    const float* wf    = (const float*)d_in[5];
    const float* wn    = (const float*)d_in[6];
    const float* w5    = (const float*)d_in[7];
    float* out = (float*)d_out;

    // ws layout (~80 MB)
    unsigned short* w3_hi = (unsigned short*)d_ws;                 // 901120 u16
    unsigned short* w3_lo = w3_hi + (size_t)NFC * K3;              // 901120 u16
    float* wxL  = (float*)(w3_lo + (size_t)NFC * K3);              // 32768 f
    float* wfhL = wxL + 32768;                                     // 4096 f
    float* wnhL = wfhL + 4096;                                     // 4096 f
    unsigned short* gBgh = (unsigned short*)(wnhL + 4096);         // 6400 u16
    unsigned short* gBgl = gBgh + 6400;                            // 6400 u16
    float* XFN  = (float*)(gBgl + 6400);                           // 20480*128 f
    float* xsp0 = XFN + (size_t)NFRAMES * 128;                     // 4096*256 f
    float* xsp1 = xsp0 + (size_t)CHUNK * NFC;                      // 4096*256 f
    unsigned short* a2h = (unsigned short*)(xsp1 + (size_t)CHUNK * NFC); // 4096*3520 u16
    unsigned short* a2l = a2h + (size_t)CHUNK * K3;                      // 4096*3520 u16

    prep_w3<<<(NFC * K3 + 255) / 256, 256, 0, stream>>>(w3, w3_hi, w3_lo);
    prep_wxL<<<(128 * 256 + 255) / 256, 256, 0, stream>>>(wf, wn, wxL);
    prep_whL<<<32, 256, 0, stream>>>(wf, wn, wfhL, wnhL);
    prep_Bg<<<25, 256, 0, stream>>>(w2, gBgh, gBgl);

    for (int f0 = 0; f0 < NFRAMES; f0 += CHUNK) {
        conv_fused<<<CHUNK / FPB, 256, 0, stream>>>(input, noise, w1, gBgh, gBgl, a2h, a2l, f0);
        gemm_fc3<<<dim3(CHUNK / 64, NFC / 64, 2), 256, 0, stream>>>(a2h, a2l, w3_hi, w3_lo, xsp0, xsp1);
        xgate_kernel<<<CHUNK / 8, 1024, 0, stream>>>(xsp0, xsp1, wxL, XFN, f0);
    }

    mgu_kernel<<<NSEQ / 4, 256, 0, stream>>>(XFN, wfhL, wnhL, w5, out);
}

// Round 13
// 500.887 us; speedup vs baseline: 2.7618x; 1.3151x over previous
//
#include <hip/hip_runtime.h>

#define H 10
#define W 11
#define C1 16
#define C2 32
#define PIX 110
#define K3 3520
#define NFC 256
#define NSEQ 2048
#define WINLEN 10
#define HID 64
#define NCLS 7
#define NFRAMES 20480
#define CHUNK 4096
#define FPB 2          // frames per conv block (2 -> 48 KB LDS -> 3 blocks/CU)

typedef __attribute__((ext_vector_type(8))) short bf16x8;
typedef __attribute__((ext_vector_type(4))) float f32x4;

__device__ __forceinline__ float clip01(float x){ return fminf(fmaxf(x, 0.f), 1.f); }
__device__ __forceinline__ float clip11(float x){ return fminf(fmaxf(x, -1.f), 1.f); }

__device__ __forceinline__ unsigned short f2bf(float x) {
    union { float f; unsigned u; } v; v.f = x;
    unsigned r = v.u + 0x7FFFu + ((v.u >> 16) & 1u);
    return (unsigned short)(r >> 16);
}
__device__ __forceinline__ float bf2f(unsigned short b) {
    union { unsigned u; float f; } v; v.u = ((unsigned)b) << 16;
    return v.f;
}

// direct global->LDS, 16B per lane (lane i lands at ldsbase + i*16)
#define GLOAD16(gp, lp) \
    __builtin_amdgcn_global_load_lds( \
        (const __attribute__((address_space(1))) unsigned int*)(gp), \
        (__attribute__((address_space(3))) unsigned int*)(lp), 16, 0, 0)

// ---------------------------------------------------------------------------
// Prep: w3 (256x3520 fp32) -> hi/lo bf16 with K PERMUTED to match a2's new
// layout: k' = pixel*32 + c2  (old k = c2*110 + pixel). GEMM is K-permutation
// invariant as long as A and B agree.
// ---------------------------------------------------------------------------
__global__ __launch_bounds__(256)
void prep_w3(const float* __restrict__ w3, unsigned short* __restrict__ hi,
             unsigned short* __restrict__ lo)
{
    int i = blockIdx.x * 256 + threadIdx.x;
    if (i < NFC * K3) {
        int n = i / K3, kp = i - n * K3;
        int c2 = kp & 31, p = kp >> 5;
        float x = w3[(size_t)n * K3 + c2 * PIX + p];
        unsigned short h = f2bf(x);
        hi[i] = h;
        lo[i] = f2bf(x - bf2f(h));
    }
}

// Prep: x-part weights of wf/wn -> wxL[kk][jj] float4 layout (fp32).
__global__ __launch_bounds__(256)
void prep_wxL(const float* __restrict__ wf, const float* __restrict__ wn,
              float* __restrict__ wxL)
{
    int i = blockIdx.x * 256 + threadIdx.x;   // 0 .. 128*256-1
    if (i < 128 * 256) {
        int kk = i >> 9, jj = (i >> 2) & 127, e = i & 3;
        int k = kk * 4 + e;
        float v = (jj < 64) ? wf[jj * 320 + k] : wn[(jj - 64) * 320 + k];
        wxL[i] = v;
    }
}

// Prep: h-part weights -> wfhL/wnhL [kk][j] float4 layout
__global__ __launch_bounds__(256)
void prep_whL(const float* __restrict__ wf, const float* __restrict__ wn,
              float* __restrict__ wfhL, float* __restrict__ wnhL)
{
    int i2 = blockIdx.x * 256 + threadIdx.x;  // 0 .. 8191
    if (i2 < 8192) {
        int sel = i2 >> 12, i = i2 & 4095;
        int kk = i >> 8, j = (i >> 2) & 63, e = i & 3;
        const float* src = sel ? wn : wf;
        float v = src[j * 320 + 256 + kk * 4 + e];
        (sel ? wnhL : wfhL)[i] = v;
    }
}

// Prep: w2 (32x16x3x3) -> shift-pair-grouped MFMA B planes.
// Bg[g][c2][k], k = s'*16+ci, shift s = 2g+s' (s=9 -> zero pad). Pitch 40.
__global__ __launch_bounds__(256)
void prep_Bg(const float* __restrict__ w2, unsigned short* __restrict__ gBgh,
             unsigned short* __restrict__ gBgl)
{
    int i = blockIdx.x * 256 + threadIdx.x;
    if (i < 6400) {
        int g = i / 1280, rem = i - g * 1280;
        int c2 = rem / 40, k = rem - c2 * 40;
        float v = 0.f;
        if (k < 32) {
            int sp = k >> 4, ci = k & 15, s = 2 * g + sp;
            if (s <= 8) v = w2[c2 * 144 + ci * 9 + s];
        }
        unsigned short hh = f2bf(v);
        gBgh[i] = hh;
        gBgl[i] = f2bf(v - bf2f(hh));
    }
}

// ---------------------------------------------------------------------------
// Kernel 1: jitter + conv1 (scalar) + conv2 (MFMA, 5 shift-pair GEMM groups).
// 256 thr = 4 waves, FPB=2 frames/block (48 KB LDS -> 3 blocks/CU; round-10
// was 70 KB -> 2 blocks/CU, Occ 18.5%, latency-bound).
// a2 stored k' = pixel*32 + c2 -> epilogue lanes 0..15 write 32B-contiguous.
// ---------------------------------------------------------------------------
__global__ __launch_bounds__(256)
void conv_fused(const float* __restrict__ input, const float* __restrict__ noise,
                const float* __restrict__ gw1,
                const unsigned short* __restrict__ gBgh,
                const unsigned short* __restrict__ gBgl,
                unsigned short* __restrict__ a2h, unsigned short* __restrict__ a2l,
                int frame0)
{
    __shared__ float s_w1[C1 * 9];
    __shared__ float xinp[FPB][160];                      // 12x13 padded + slack
    __shared__ __align__(16) unsigned short a1T_h[FPB][2560];  // 160 q x 16 ci
    __shared__ __align__(16) unsigned short a1T_l[FPB][2560];
    __shared__ __align__(16) unsigned short Bg_h[6400];   // 5 x 32 x pitch40
    __shared__ __align__(16) unsigned short Bg_l[6400];

    const int tid = threadIdx.x;
    const int fbase = frame0 + blockIdx.x * FPB;

    for (int i = tid; i < C1 * 9; i += 256) s_w1[i] = gw1[i];
    for (int i = tid; i < 800; i += 256) {
        ((uint4*)Bg_h)[i] = ((const uint4*)gBgh)[i];
        ((uint4*)Bg_l)[i] = ((const uint4*)gBgl)[i];
    }
    for (int i = tid; i < FPB * 160; i += 256) (&xinp[0][0])[i] = 0.f;
    {
        uint4 z = {0, 0, 0, 0};
        uint4* ph = (uint4*)&a1T_h[0][0];
        uint4* pl = (uint4*)&a1T_l[0][0];
        for (int i = tid; i < FPB * 2560 / 8; i += 256) { ph[i] = z; pl[i] = z; }
    }
    __syncthreads();

    // jitter into padded 12x13
    for (int i = tid; i < FPB * PIX; i += 256) {
        int fl = i / PIX, p = i - fl * PIX;
        int y = p / W, x = p - y * W;
        size_t g = (size_t)(fbase + fl) * PIX + p;
        xinp[fl][(y + 1) * 13 + x + 1] = input[g] * (1.f + noise[g] / 20.f);
    }
    __syncthreads();

    // conv1: items (fl, p, c) c-minor -> swizzled a1T writes
    for (int i = tid; i < FPB * 1760; i += 256) {
        int fl = i / 1760, rem = i - fl * 1760;
        int p = rem >> 4, c = rem & 15;
        int y = p / W, x = p - y * W;
        const float* wr = &s_w1[c * 9];
        const float* xp = &xinp[fl][y * 13 + x];
        float acc = xp[0]*wr[0] + xp[1]*wr[1] + xp[2]*wr[2]
                  + xp[13]*wr[3] + xp[14]*wr[4] + xp[15]*wr[5]
                  + xp[26]*wr[6] + xp[27]*wr[7] + xp[28]*wr[8];
        float v = clip01(acc);
        unsigned short hh = f2bf(v);
        int q = (y + 1) * 13 + (x + 1);
        int col = c ^ ((q & 4) << 1);      // ((q>>2)&1)<<3
        a1T_h[fl][q * 16 + col] = hh;
        a1T_l[fl][q * 16 + col] = f2bf(v - bf2f(hh));
    }
    __syncthreads();

    // conv2 via MFMA
    const int lane = tid & 63;
    const int wid  = tid >> 6;           // 4 waves; wave w: m-tiles {2w,2w+1}
    const int lr   = lane & 15;
    const int ci0  = (lane & 16) ? 8 : 0;
    const int khalf = (lane >> 4) * 8;   // B k-offset 0/8/16/24

    for (int fl = 0; fl < FPB; ++fl) {
        f32x4 acc[2][2];
        #pragma unroll
        for (int mi = 0; mi < 2; ++mi)
            #pragma unroll
            for (int ni = 0; ni < 2; ++ni) { f32x4 z = {0,0,0,0}; acc[mi][ni] = z; }

        #pragma unroll
        for (int g = 0; g < 5; ++g) {
            const int s0 = 2 * g, s1 = 2 * g + 1;
            const int offA = (s0 / 3) * 13 + s0 % 3;
            const int offB = (s1 <= 8) ? (s1 / 3) * 13 + s1 % 3 : 0;
            const int offl = (lane & 32) ? offB : offA;

            bf16x8 ah[2], al2[2], bh[2], bl[2];
            #pragma unroll
            for (int mi = 0; mi < 2; ++mi) {
                int q = (wid * 2 + mi) * 16 + lr + offl;
                int cs = q * 16 + (ci0 ^ ((q & 4) << 1));
                ah[mi]  = *(const bf16x8*)&a1T_h[fl][cs];
                al2[mi] = *(const bf16x8*)&a1T_l[fl][cs];
            }
            #pragma unroll
            for (int ni = 0; ni < 2; ++ni) {
                int bs = g * 1280 + (ni * 16 + lr) * 40 + khalf;
                bh[ni] = *(const bf16x8*)&Bg_h[bs];
                bl[ni] = *(const bf16x8*)&Bg_l[bs];
            }
            #pragma unroll
            for (int mi = 0; mi < 2; ++mi)
                #pragma unroll
                for (int ni = 0; ni < 2; ++ni) {
                    acc[mi][ni] = __builtin_amdgcn_mfma_f32_16x16x32_bf16(ah[mi],  bh[ni], acc[mi][ni], 0, 0, 0);
                    acc[mi][ni] = __builtin_amdgcn_mfma_f32_16x16x32_bf16(ah[mi],  bl[ni], acc[mi][ni], 0, 0, 0);
                    acc[mi][ni] = __builtin_amdgcn_mfma_f32_16x16x32_bf16(al2[mi], bh[ni], acc[mi][ni], 0, 0, 0);
                }
        }

        // epilogue: row m = padded pixel (y=m/13, x=m%13, valid x<11),
        // store at k' = (y*11+x)*32 + c2 -> lanes 0..15 contiguous 32B
        const int fr = blockIdx.x * FPB + fl;
        #pragma unroll
        for (int mi = 0; mi < 2; ++mi) {
            int m0 = (wid * 2 + mi) * 16 + (lane >> 4) * 4;
            #pragma unroll
            for (int ni = 0; ni < 2; ++ni) {
                #pragma unroll
                for (int r = 0; r < 4; ++r) {
                    int m = m0 + r;
                    int y = m / 13, x = m - y * 13;
                    if (x < W) {
                        float v = clip01(acc[mi][ni][r]);
                        unsigned short hh = f2bf(v);
                        size_t addr = (size_t)fr * K3 + (y * W + x) * 32 + ni * 16 + lr;
                        a2h[addr] = hh;
                        a2l[addr] = f2bf(v - bf2f(hh));
                    }
                }
            }
        }
    }
}

// ---------------------------------------------------------------------------
// Kernel 2: fc3 via bf16x3 split MFMA, global_load_lds staging (round-9,
// verified). K-order is the permuted k' on both A and B -> result identical.
// ---------------------------------------------------------------------------
__global__ __launch_bounds__(256)
void gemm_fc3(const unsigned short* __restrict__ Ah, const unsigned short* __restrict__ Al,
              const unsigned short* __restrict__ Bh, const unsigned short* __restrict__ Bl,
              float* __restrict__ xsp0, float* __restrict__ xsp1)
{
    __shared__ unsigned short lds[4][64 * 64];   // Ah, Al, Bh, Bl planes

    const int tid  = threadIdx.x;
    const int lane = tid & 63;
    const int wid  = tid >> 6;            // wave 0..3
    const int wm   = wid >> 1, wn = wid & 1;
    const int bm   = blockIdx.x * 64;
    const int bn   = blockIdx.y * 64;
    const int z    = blockIdx.z;
    const int kb0  = z * 1792;
    const int NT   = z ? 27 : 28;
    const int lr   = lane & 15;
    const int ko   = (lane >> 4) * 8;

    const unsigned short* gsrc;
    {
        const unsigned short* bases[4] = {Ah, Al, Bh, Bl};
        int row0 = (wid < 2) ? bm : bn;
        gsrc = bases[wid] + (size_t)row0 * K3;
    }
    const int srow = lane >> 3;
    const int scol = ((lane & 7) ^ srow) << 3;

    f32x4 acc[2][2];
    #pragma unroll
    for (int mi = 0; mi < 2; ++mi)
        #pragma unroll
        for (int ni = 0; ni < 2; ++ni) { f32x4 zz = {0,0,0,0}; acc[mi][ni] = zz; }

    for (int t = 0; t < NT; ++t) {
        const int k0 = kb0 + t * 64;
        #pragma unroll
        for (int i = 0; i < 8; ++i) {
            GLOAD16(gsrc + (size_t)(i * 8 + srow) * K3 + k0 + scol,
                    &lds[wid][i * 512]);
        }
        __syncthreads();

        #pragma unroll
        for (int kk = 0; kk < 64; kk += 32) {
            bf16x8 ah[2], al2[2], bh[2], bl[2];
            #pragma unroll
            for (int mi = 0; mi < 2; ++mi) {
                int row = wm * 32 + mi * 16 + lr;
                int cs  = (kk + ko) ^ ((row & 7) << 3);
                ah[mi]  = *(const bf16x8*)&lds[0][row * 64 + cs];
                al2[mi] = *(const bf16x8*)&lds[1][row * 64 + cs];
            }
            #pragma unroll
            for (int ni = 0; ni < 2; ++ni) {
                int row = wn * 32 + ni * 16 + lr;
                int cs  = (kk + ko) ^ ((row & 7) << 3);
                bh[ni] = *(const bf16x8*)&lds[2][row * 64 + cs];
                bl[ni] = *(const bf16x8*)&lds[3][row * 64 + cs];
            }
            #pragma unroll
            for (int mi = 0; mi < 2; ++mi)
                #pragma unroll
                for (int ni = 0; ni < 2; ++ni) {
                    acc[mi][ni] = __builtin_amdgcn_mfma_f32_16x16x32_bf16(ah[mi],  bh[ni], acc[mi][ni], 0, 0, 0);
                    acc[mi][ni] = __builtin_amdgcn_mfma_f32_16x16x32_bf16(ah[mi],  bl[ni], acc[mi][ni], 0, 0, 0);
                    acc[mi][ni] = __builtin_amdgcn_mfma_f32_16x16x32_bf16(al2[mi], bh[ni], acc[mi][ni], 0, 0, 0);
                }
        }
        __syncthreads();
    }

    float* xsp = z ? xsp1 : xsp0;
    #pragma unroll
    for (int mi = 0; mi < 2; ++mi) {
        int row0 = bm + wm * 32 + mi * 16 + (lane >> 4) * 4;
        #pragma unroll
        for (int ni = 0; ni < 2; ++ni) {
            int col = bn + wn * 32 + ni * 16 + lr;
            #pragma unroll
            for (int r = 0; r < 4; ++r)
                xsp[(size_t)(row0 + r) * NFC + col] = acc[mi][ni][r];
        }
    }
}

// ---------------------------------------------------------------------------
// Kernel 3: XFN = clip01(xsp0+xsp1) @ Wx^T  (per chunk)
// ---------------------------------------------------------------------------
__global__ __launch_bounds__(1024)
void xgate_kernel(const float* __restrict__ xsp0, const float* __restrict__ xsp1,
                  const float* __restrict__ wxL, float* __restrict__ XFN, int frame0)
{
    __shared__ float xrow[8][NFC];
    const int tid = threadIdx.x;
    const int r8 = tid >> 7;
    const int j  = tid & 127;

    #pragma unroll
    for (int p = 0; p < 2; ++p) {
        int i = tid + p * 1024;
        int r = i >> 8, c = i & 255;
        size_t src = (size_t)(blockIdx.x * 8 + r) * NFC + c;
        xrow[r][c] = clip01(xsp0[src] + xsp1[src]);
    }
    __syncthreads();

    const float4* wx4 = (const float4*)wxL;
    float af = 0.f;
    #pragma unroll 8
    for (int kk = 0; kk < 64; ++kk) {
        float4 w4 = wx4[kk * 128 + j];
        float4 x4 = *(const float4*)&xrow[r8][kk * 4];
        af += w4.x * x4.x + w4.y * x4.y + w4.z * x4.z + w4.w * x4.w;
    }
    XFN[(size_t)(frame0 + blockIdx.x * 8 + r8) * 128 + j] = af;
}

// ---------------------------------------------------------------------------
// Kernel 4: MGU recurrence (h-part only) + fc5
// ---------------------------------------------------------------------------
__global__ __launch_bounds__(256)
void mgu_kernel(const float* __restrict__ XFN, const float* __restrict__ wfhL_g,
                const float* __restrict__ wnhL_g, const float* __restrict__ w5,
                float* __restrict__ out)
{
    __shared__ float4 wfh[16 * 64];
    __shared__ float4 wnh[16 * 64];
    __shared__ float hs[4][HID];
    __shared__ float fhs[4][HID];

    const int tid = threadIdx.x;
    const int s   = tid >> 6;
    const int j   = tid & 63;
    const int seq = blockIdx.x * 4 + s;

    const float4* wf4 = (const float4*)wfhL_g;
    const float4* wn4 = (const float4*)wnhL_g;
    for (int i = tid; i < 1024; i += 256) { wfh[i] = wf4[i]; wnh[i] = wn4[i]; }
    hs[s][j] = 0.f;
    float hreg = 0.f;
    __syncthreads();

    for (int t = 0; t < WINLEN; ++t) {
        size_t xr = (size_t)(seq * WINLEN + t) * 128;
        float af = XFN[xr + j];
        #pragma unroll
        for (int kk = 0; kk < 16; ++kk) {
            float4 w4 = wfh[kk * 64 + j];
            float4 h4 = *(const float4*)&hs[s][kk * 4];
            af += w4.x * h4.x + w4.y * h4.y + w4.z * h4.z + w4.w * h4.w;
        }
        float f = clip01(af * (1.f / 6.f) + 0.5f);
        fhs[s][j] = f * hreg;
        __syncthreads();

        float an = XFN[xr + 64 + j];
        #pragma unroll
        for (int kk = 0; kk < 16; ++kk) {
            float4 w4 = wnh[kk * 64 + j];
            float4 h4 = *(const float4*)&fhs[s][kk * 4];
            an += w4.x * h4.x + w4.y * h4.y + w4.z * h4.z + w4.w * h4.w;
        }
        float nv = clip11(an);
        hreg = (1.f - f) * hreg + f * nv;
        hs[s][j] = hreg;
        __syncthreads();
    }

    if (tid < 4 * NCLS) {
        int s2 = tid / NCLS, c = tid - s2 * NCLS;
        float a = 0.f;
        #pragma unroll
        for (int k = 0; k < HID; ++k) a += hs[s2][k] * w5[c * HID + k];
        out[(size_t)(blockIdx.x * 4 + s2) * NCLS + c] = clip11(a);
    }
}

// ---------------------------------------------------------------------------
extern "C" void kernel_launch(void* const* d_in, const int* in_sizes, int n_in,
                              void* d_out, int out_size, void* d_ws, size_t ws_size,
                              hipStream_t stream)
{
    const float* input = (const float*)d_in[0];
    const float* noise = (const float*)d_in[1];
    const float* w1    = (const float*)d_in[2];
    const float* w2    = (const float*)d_in[3];
    const float* w3    = (const float*)d_in[4];
    const float* wf    = (const float*)d_in[5];
    const float* wn    = (const float*)d_in[6];
    const float* w5    = (const float*)d_in[7];
    float* out = (float*)d_out;

    // ws layout (~80 MB)
    unsigned short* w3_hi = (unsigned short*)d_ws;                 // 901120 u16
    unsigned short* w3_lo = w3_hi + (size_t)NFC * K3;              // 901120 u16
    float* wxL  = (float*)(w3_lo + (size_t)NFC * K3);              // 32768 f
    float* wfhL = wxL + 32768;                                     // 4096 f
    float* wnhL = wfhL + 4096;                                     // 4096 f
    unsigned short* gBgh = (unsigned short*)(wnhL + 4096);         // 6400 u16
    unsigned short* gBgl = gBgh + 6400;                            // 6400 u16
    float* XFN  = (float*)(gBgl + 6400);                           // 20480*128 f
    float* xsp0 = XFN + (size_t)NFRAMES * 128;                     // 4096*256 f
    float* xsp1 = xsp0 + (size_t)CHUNK * NFC;                      // 4096*256 f
    unsigned short* a2h = (unsigned short*)(xsp1 + (size_t)CHUNK * NFC); // 4096*3520 u16
    unsigned short* a2l = a2h + (size_t)CHUNK * K3;                      // 4096*3520 u16

    prep_w3<<<(NFC * K3 + 255) / 256, 256, 0, stream>>>(w3, w3_hi, w3_lo);
    prep_wxL<<<(128 * 256 + 255) / 256, 256, 0, stream>>>(wf, wn, wxL);
    prep_whL<<<32, 256, 0, stream>>>(wf, wn, wfhL, wnhL);
    prep_Bg<<<25, 256, 0, stream>>>(w2, gBgh, gBgl);

    for (int f0 = 0; f0 < NFRAMES; f0 += CHUNK) {
        conv_fused<<<CHUNK / FPB, 256, 0, stream>>>(input, noise, w1, gBgh, gBgl, a2h, a2l, f0);
        gemm_fc3<<<dim3(CHUNK / 64, NFC / 64, 2), 256, 0, stream>>>(a2h, a2l, w3_hi, w3_lo, xsp0, xsp1);
        xgate_kernel<<<CHUNK / 8, 1024, 0, stream>>>(xsp0, xsp1, wxL, XFN, f0);
    }

    mgu_kernel<<<NSEQ / 4, 256, 0, stream>>>(XFN, wfhL, wnhL, w5, out);
}